// Round 1
// baseline (1494.332 us; speedup 1.0000x reference)
//
#include <hip/hip_runtime.h>
#include <math.h>

#define NH 4
#define ND 64
#define NC 128
#define NHD 256
#define NM 30
#define NK 10
#define EPSF 1e-6f
#define RATIO 0.18257418583505536f    // 1/sqrt(30)
#define QKSCALE 0.7071067811865476f   // inv_sqrt_tau(=2) * 64^{-1/4}(=0.353553)
#define S3 64                         // kvs reduction segments

__device__ __forceinline__ unsigned f2ord(float f){ unsigned b=__float_as_uint(f); return (b&0x80000000u)?~b:(b|0x80000000u); }
__device__ __forceinline__ float ord2f(unsigned u){ return __uint_as_float((u&0x80000000u)?(u&0x7fffffffu):~u); }

__global__ void k_init(unsigned* mxk_u){ if (threadIdx.x < NH) mxk_u[threadIdx.x] = 0u; }

// ---------------------------------------------------------------------------
// K1: fused QKV projection + q-features (qp) + dd_k/diag_k + v.  16 nodes/block.
// ---------------------------------------------------------------------------
__global__ __launch_bounds__(256) void k_qkv(
    const float* __restrict__ z, const float* __restrict__ proj,
    const float* __restrict__ Wq, const float* __restrict__ bq,
    const float* __restrict__ Wk, const float* __restrict__ bk,
    const float* __restrict__ Wv, const float* __restrict__ bv,
    float* __restrict__ qp, float* __restrict__ dd_k, float* __restrict__ diag_k,
    float* __restrict__ v_out, int N)
{
    const int NB = 16;
    __shared__ float zs[NB*NC];        // 8 KB
    __shared__ float xs[NB*8*65];      // 33.3 KB   row = nb*8 + qk*4 + h, stride 65 (bank-safe)
    __shared__ float proj_s[NM*65];    // 7.8 KB
    __shared__ float ddq_s[NB*120];    // 7.7 KB
    __shared__ float diagq_s[NB*4];
    int tid = threadIdx.x;
    int n0 = blockIdx.x * NB;

    for (int i = tid; i < NB*NC; i += 256) {
        int n = n0 + i / NC;
        zs[i] = (n < N) ? z[(size_t)n0*NC + i] : 0.f;
    }
    for (int i = tid; i < NM*ND; i += 256)
        proj_s[(i/ND)*65 + (i%ND)] = proj[i];
    __syncthreads();

    // qkv for output column `tid` over 16 nodes
    float accq[NB], acck[NB], accv[NB];
    #pragma unroll
    for (int nb=0;nb<NB;nb++){ accq[nb]=0.f; acck[nb]=0.f; accv[nb]=0.f; }
    float bqv = bq[tid], bkv = bk[tid], bvv = bv[tid];
    for (int c=0;c<NC;c++) {
        float wq = Wq[c*NHD+tid], wk = Wk[c*NHD+tid], wv = Wv[c*NHD+tid];
        #pragma unroll
        for (int nb=0;nb<NB;nb++) {
            float zc = zs[nb*NC+c];
            accq[nb] = fmaf(zc, wq, accq[nb]);
            acck[nb] = fmaf(zc, wk, acck[nb]);
            accv[nb] = fmaf(zc, wv, accv[nb]);
        }
    }
    int hcol = tid >> 6, dcol = tid & 63;
    for (int nb=0;nb<NB;nb++) {
        int n = n0+nb;
        if (n < N) v_out[(size_t)n*NHD + tid] = accv[nb] + bvv;
        xs[(nb*8 + hcol)*65 + dcol]     = (accq[nb] + bqv) * QKSCALE;
        xs[(nb*8 + 4 + hcol)*65 + dcol] = (acck[nb] + bkv) * QKSCALE;
    }
    __syncthreads();

    // dd dot products: 16 nodes x {q,k} x 4h x 30m = 3840 dots of length 64
    for (int i = tid; i < NB*240; i += 256) {
        int nb = i / 240, r = i % 240;
        int qk = r / 120, hm = r % 120;
        int hh = hm / 30, m = hm % 30;
        const float* xrow = &xs[(nb*8 + qk*4 + hh)*65];
        const float* prow = &proj_s[m*65];
        float s = 0.f;
        #pragma unroll
        for (int d=0; d<ND; d++) s = fmaf(xrow[d], prow[d], s);
        if (qk == 0) ddq_s[nb*120 + hm] = s;
        else { int n = n0+nb; if (n < N) dd_k[(size_t)hh*N*NM + (size_t)n*NM + m] = s; }
    }
    // diag = 0.5 * sum(x^2): 16 x 2 x 4 = 128 values
    if (tid < NB*8) {
        int nb = tid/8, r = tid%8, qk = r/4, hh = r%4;
        const float* xrow = &xs[(nb*8 + qk*4 + hh)*65];
        float s = 0.f;
        #pragma unroll
        for (int d=0; d<ND; d++) s = fmaf(xrow[d], xrow[d], s);
        s *= 0.5f;
        if (qk == 0) diagq_s[nb*4+hh] = s;
        else { int n = n0+nb; if (n < N) diag_k[n*4+hh] = s; }
    }
    __syncthreads();

    // qp = ratio*(exp(dd - diag - max_m dd) + eps)
    for (int i = tid; i < NB*120; i += 256) {
        int nb = i/120, hm = i%120, hh = hm/30;
        int n = n0+nb;
        if (n >= N) continue;
        float mx = -3.0e38f;
        #pragma unroll
        for (int j=0;j<NM;j++) mx = fmaxf(mx, ddq_s[nb*120 + hh*30 + j]);
        float val = RATIO * (__expf(ddq_s[nb*120+hm] - diagq_s[nb*4+hh] - mx) + EPSF);
        qp[(size_t)n*120 + hm] = val;
    }
}

// ---------------------------------------------------------------------------
// K1.5: global max of dd_k per head
// ---------------------------------------------------------------------------
__global__ __launch_bounds__(256) void k_maxred(const float* __restrict__ dd_k,
                                                unsigned* __restrict__ mxk_u, int N)
{
    int hh = blockIdx.y;
    size_t len = (size_t)N*NM;
    const float* p = dd_k + (size_t)hh*len;
    float mx = -3.0e38f;
    for (size_t i = (size_t)blockIdx.x*256 + threadIdx.x; i < len; i += (size_t)gridDim.x*256)
        mx = fmaxf(mx, p[i]);
    for (int o=32;o>0;o>>=1) mx = fmaxf(mx, __shfl_down(mx, o));
    __shared__ float wmax[4];
    if ((threadIdx.x & 63) == 0) wmax[threadIdx.x >> 6] = mx;
    __syncthreads();
    if (threadIdx.x == 0) {
        mx = fmaxf(fmaxf(wmax[0],wmax[1]), fmaxf(wmax[2],wmax[3]));
        atomicMax(&mxk_u[hh], f2ord(mx));
    }
}

// ---------------------------------------------------------------------------
// K2: kp = ratio*(exp(dd_k - diag_k - mxk) + eps), plus per-block kp_sum partials
// 128 nodes per block.
// ---------------------------------------------------------------------------
__global__ __launch_bounds__(256) void k_kp(const float* __restrict__ dd_k,
    const float* __restrict__ diag_k, const unsigned* __restrict__ mxk_u,
    float* __restrict__ kp, float* __restrict__ kp_part, int N)
{
    __shared__ float psum[120];
    int tid = threadIdx.x;
    if (tid < 120) psum[tid] = 0.f;
    float mxk[NH];
    #pragma unroll
    for (int hh=0;hh<NH;hh++) mxk[hh] = ord2f(mxk_u[hh]);
    __syncthreads();
    int n0 = blockIdx.x * 128;
    for (int r = 0; r < 60; r++) {
        int idx = r*256 + tid;          // covers 128*120
        int nl = idx / 120, hm = idx % 120;
        int n = n0 + nl;
        if (n >= N) break;
        int hh = hm/30, m = hm%30;
        float val = RATIO * (__expf(dd_k[(size_t)hh*N*NM + (size_t)n*NM + m]
                                    - diag_k[n*4+hh] - mxk[hh]) + EPSF);
        kp[(size_t)n*120 + hm] = val;
        atomicAdd(&psum[hm], val);
    }
    __syncthreads();
    if (tid < 120) kp_part[blockIdx.x*120 + tid] = psum[tid];
}

__global__ void k_kpsred(const float* __restrict__ kp_part, float* __restrict__ kp_sum, int nblk){
    int t = threadIdx.x;
    if (t < 120) {
        float s = 0.f;
        for (int b=0;b<nblk;b++) s += kp_part[b*120+t];
        kp_sum[t] = s;
    }
}

// ---------------------------------------------------------------------------
// K3: kvs partials.  block = (seg, k, h), 64 threads (thread = d).
// acc[m] += kp[n,h,m]*exp(g[n,h,k]) * v[n,h,d];  also kg partial on lanes<30.
// ---------------------------------------------------------------------------
__global__ __launch_bounds__(64) void k_kvs(const float* __restrict__ kp,
    const float* __restrict__ gum, const float* __restrict__ v,
    float* __restrict__ kvs_part, float* __restrict__ kg_part, int N)
{
    int seg = blockIdx.x, k = blockIdx.y, hh = blockIdx.z;
    int tid = threadIdx.x;
    int ns = (N + S3 - 1)/S3;
    int n0 = seg*ns, n1 = min(N, n0+ns);
    __shared__ float egs[64];
    __shared__ float kpeg[64*32];
    float acc[NM];
    #pragma unroll
    for (int m=0;m<NM;m++) acc[m]=0.f;
    float acckg = 0.f;
    for (int nc = n0; nc < n1; nc += 64) {
        int cn = min(64, n1-nc);
        __syncthreads();
        if (tid < cn) egs[tid] = __expf(gum[(size_t)(nc+tid)*(NH*NK) + hh*NK + k]);
        __syncthreads();
        for (int i = tid; i < cn*32; i += 64) {
            int nl = i >> 5, mm = i & 31;
            kpeg[i] = (mm < NM) ? kp[(size_t)(nc+nl)*120 + hh*30 + mm] * egs[nl] : 0.f;
        }
        __syncthreads();
        for (int nl = 0; nl < cn; nl++) {
            float vd = v[(size_t)(nc+nl)*NHD + hh*64 + tid];
            const float* kr = &kpeg[nl*32];
            #pragma unroll
            for (int m=0;m<NM;m++) acc[m] = fmaf(kr[m], vd, acc[m]);
            if (tid < NM) acckg += kr[tid];
        }
    }
    size_t base = (size_t)(hh*NK + k)*S3 + seg;
    for (int m=0;m<NM;m++) kvs_part[base*1920 + m*64 + tid] = acc[m];
    if (tid < NM) kg_part[base*30 + tid] = acckg;
}

__global__ void k_kvsred(const float* __restrict__ kvs_part, float* __restrict__ kvs){
    int o = blockIdx.x*256 + threadIdx.x;       // 76800 outputs
    if (o >= NH*NK*1920) return;
    int hk = o / 1920, md = o % 1920;
    float s = 0.f;
    for (int sg=0; sg<S3; sg++) s += kvs_part[((size_t)hk*S3 + sg)*1920 + md];
    kvs[o] = s;
}
__global__ void k_kgred(const float* __restrict__ kg_part, float* __restrict__ kg_sum){
    int o = blockIdx.x*256 + threadIdx.x;       // 1200 outputs
    if (o >= NH*NK*30) return;
    int hk = o/30, m = o%30;
    float s = 0.f;
    for (int sg=0; sg<S3; sg++) s += kg_part[((size_t)hk*S3+sg)*30 + m];
    kg_sum[o] = s;
}

// ---------------------------------------------------------------------------
// K5: per-node z_out (mean_k z_num/z_den) + den_node.  blockIdx.y = head.
// kvs[h] staged in LDS in two k-halves (38.4 KB).
// ---------------------------------------------------------------------------
__global__ __launch_bounds__(256) void k_z(const float* __restrict__ qp,
    const float* __restrict__ kvs, const float* __restrict__ kg_sum,
    const float* __restrict__ kp_sum, float* __restrict__ den_node,
    float* __restrict__ z_out, int N)
{
    __shared__ float kvs_s[5*30*64];
    __shared__ float kg_s[NK*30];
    __shared__ float kps_s[30];
    int tid = threadIdx.x;
    int hh = blockIdx.y;
    int n = blockIdx.x*256 + tid;
    bool valid = (n < N);

    for (int i=tid;i<300;i+=256) kg_s[i] = kg_sum[hh*300+i];
    if (tid<30) kps_s[tid] = kp_sum[hh*30+tid];
    for (int i=tid;i<9600;i+=256) kvs_s[i] = kvs[(size_t)hh*19200 + i];
    __syncthreads();

    float qv[NM]; float scale[NK];
    if (valid) {
        const float2* q2 = (const float2*)(qp + (size_t)n*120 + hh*30);
        #pragma unroll
        for (int j=0;j<15;j++){ float2 t = q2[j]; qv[2*j]=t.x; qv[2*j+1]=t.y; }
        float dn = 0.f;
        #pragma unroll
        for (int m=0;m<NM;m++) dn = fmaf(qv[m], kps_s[m], dn);
        den_node[(size_t)n*4 + hh] = dn;
        #pragma unroll
        for (int k=0;k<NK;k++){
            float s=0.f;
            #pragma unroll
            for (int m=0;m<NM;m++) s = fmaf(qv[m], kg_s[k*30+m], s);
            scale[k] = (1.0f/NK) / s;
        }
    }
    float4 zacc[16];
    #pragma unroll
    for (int i=0;i<16;i++) zacc[i] = make_float4(0.f,0.f,0.f,0.f);

    if (valid) {
        for (int k=0;k<5;k++)
            for (int m=0;m<NM;m++){
                float w = qv[m]*scale[k];
                const float4* kr = (const float4*)&kvs_s[(k*30+m)*64];
                #pragma unroll
                for (int d4=0; d4<16; d4++){
                    float4 kv = kr[d4];
                    zacc[d4].x = fmaf(w, kv.x, zacc[d4].x);
                    zacc[d4].y = fmaf(w, kv.y, zacc[d4].y);
                    zacc[d4].z = fmaf(w, kv.z, zacc[d4].z);
                    zacc[d4].w = fmaf(w, kv.w, zacc[d4].w);
                }
            }
    }
    __syncthreads();
    for (int i=tid;i<9600;i+=256) kvs_s[i] = kvs[(size_t)hh*19200 + 9600 + i];
    __syncthreads();
    if (valid) {
        for (int k=0;k<5;k++)
            for (int m=0;m<NM;m++){
                float w = qv[m]*scale[5+k];
                const float4* kr = (const float4*)&kvs_s[(k*30+m)*64];
                #pragma unroll
                for (int d4=0; d4<16; d4++){
                    float4 kv = kr[d4];
                    zacc[d4].x = fmaf(w, kv.x, zacc[d4].x);
                    zacc[d4].y = fmaf(w, kv.y, zacc[d4].y);
                    zacc[d4].z = fmaf(w, kv.z, zacc[d4].z);
                    zacc[d4].w = fmaf(w, kv.w, zacc[d4].w);
                }
            }
        float4* zo = (float4*)(z_out + (size_t)n*NHD + hh*64);
        #pragma unroll
        for (int d4=0;d4<16;d4++) zo[d4] = zacc[d4];
    }
}

// ---------------------------------------------------------------------------
// K6: out = z_out @ Wo + b.  32 nodes/block, Wo + z staged by j-halves.
// ---------------------------------------------------------------------------
__global__ __launch_bounds__(256) void k_wo(const float* __restrict__ z_out,
    const float* __restrict__ Wo, const float* __restrict__ Wob,
    float* __restrict__ out, int N)
{
    __shared__ float wo_s[128*64];   // 32 KB
    __shared__ float z_s[32*128];    // 16 KB
    int tid = threadIdx.x;
    int n0 = blockIdx.x*32;
    int col4 = tid & 15, nl = tid >> 4;   // nodes nl and nl+16
    float4 acc0 = make_float4(0.f,0.f,0.f,0.f), acc1 = acc0;
    for (int jh=0; jh<2; jh++){
        __syncthreads();
        for (int i=tid;i<128*64;i+=256) wo_s[i] = Wo[jh*128*64 + i];
        for (int i=tid;i<32*128;i+=256){
            int nn = n0 + i/128;
            z_s[i] = (nn<N)? z_out[(size_t)nn*NHD + jh*128 + (i%128)] : 0.f;
        }
        __syncthreads();
        for (int j=0;j<128;j++){
            float4 w4 = *(const float4*)&wo_s[j*64 + col4*4];
            float zv0 = z_s[nl*128 + j];
            float zv1 = z_s[(nl+16)*128 + j];
            acc0.x = fmaf(zv0, w4.x, acc0.x); acc0.y = fmaf(zv0, w4.y, acc0.y);
            acc0.z = fmaf(zv0, w4.z, acc0.z); acc0.w = fmaf(zv0, w4.w, acc0.w);
            acc1.x = fmaf(zv1, w4.x, acc1.x); acc1.y = fmaf(zv1, w4.y, acc1.y);
            acc1.z = fmaf(zv1, w4.z, acc1.z); acc1.w = fmaf(zv1, w4.w, acc1.w);
        }
    }
    float4 bv = *(const float4*)&Wob[col4*4];
    int nA = n0+nl, nB = n0+nl+16;
    if (nA < N) {
        float4 r = make_float4(acc0.x+bv.x, acc0.y+bv.y, acc0.z+bv.z, acc0.w+bv.w);
        *(float4*)(out + (size_t)nA*ND + col4*4) = r;
    }
    if (nB < N) {
        float4 r = make_float4(acc1.x+bv.x, acc1.y+bv.y, acc1.z+bv.z, acc1.w+bv.w);
        *(float4*)(out + (size_t)nB*ND + col4*4) = r;
    }
}

// ---------------------------------------------------------------------------
// K7: edge attention weights.  one thread per edge.
// ---------------------------------------------------------------------------
__global__ __launch_bounds__(256) void k_edge(const int* __restrict__ ei,
    const float* __restrict__ qp, const float* __restrict__ kp,
    const float* __restrict__ den_node, float* __restrict__ A, int E)
{
    int e = blockIdx.x*256 + threadIdx.x;
    if (e >= E) return;
    int s = ei[e], t = ei[E + e];
    const float4* rq = (const float4*)(qp + (size_t)t*120);
    const float4* rk = (const float4*)(kp + (size_t)s*120);
    float num[NH] = {0.f,0.f,0.f,0.f};
    #pragma unroll
    for (int j=0;j<30;j++){
        float4 a = rq[j], b = rk[j];
        num[(4*j)/30]   = fmaf(a.x, b.x, num[(4*j)/30]);
        num[(4*j+1)/30] = fmaf(a.y, b.y, num[(4*j+1)/30]);
        num[(4*j+2)/30] = fmaf(a.z, b.z, num[(4*j+2)/30]);
        num[(4*j+3)/30] = fmaf(a.w, b.w, num[(4*j+3)/30]);
    }
    float4 dn = *(const float4*)(den_node + (size_t)t*4);
    float4 res = make_float4(num[0]/dn.x, num[1]/dn.y, num[2]/dn.z, num[3]/dn.w);
    *(float4*)(A + (size_t)e*4) = res;
}

// ---------------------------------------------------------------------------
extern "C" void kernel_launch(void* const* d_in, const int* in_sizes, int n_in,
                              void* d_out, int out_size, void* d_ws, size_t ws_size,
                              hipStream_t stream)
{
    const float* z    = (const float*)d_in[0];
    const int*   ei   = (const int*)d_in[1];
    const float* gum  = (const float*)d_in[2];
    const float* proj = (const float*)d_in[3];
    const float* Wq   = (const float*)d_in[4];
    const float* bq   = (const float*)d_in[5];
    const float* Wk   = (const float*)d_in[6];
    const float* bk   = (const float*)d_in[7];
    const float* Wv   = (const float*)d_in[8];
    const float* bv   = (const float*)d_in[9];
    const float* Wo   = (const float*)d_in[10];
    const float* Wob  = (const float*)d_in[11];
    int N = in_sizes[0] / NC;
    int E = in_sizes[1] / 2;

    float* ws = (float*)d_ws;
    size_t o = 0;
    float* qp       = ws + o; o += (size_t)N*120;
    float* kp       = ws + o; o += (size_t)N*120;
    float* vbuf     = ws + o; float* z_out = vbuf;       o += (size_t)N*NHD;   // z_out reuses v (disjoint lifetimes)
    float* dd_k     = ws + o; float* kvs_part = dd_k;    o += (size_t)NH*N*NM; // kvs_part (4.92M) reuses dd_k (6M)
    float* diag_k   = ws + o; o += (size_t)N*4;
    float* den_node = ws + o; o += (size_t)N*4;
    unsigned* mxk_u = (unsigned*)(ws + o); o += 4;
    int nkb = (N+127)/128;
    float* kp_part  = ws + o; o += (size_t)nkb*120;
    float* kp_sum   = ws + o; o += 120;
    float* kg_part  = ws + o; o += (size_t)NH*NK*S3*30;
    float* kvs      = ws + o; o += (size_t)NH*NK*1920;
    float* kg_sum   = ws + o; o += (size_t)NH*NK*30;

    float* out = (float*)d_out;
    float* A   = out + (size_t)N*ND;

    k_init<<<dim3(1), dim3(64), 0, stream>>>(mxk_u);
    k_qkv<<<dim3((N+15)/16), dim3(256), 0, stream>>>(z, proj, Wq, bq, Wk, bk, Wv, bv,
                                                     qp, dd_k, diag_k, vbuf, N);
    k_maxred<<<dim3(48,4), dim3(256), 0, stream>>>(dd_k, mxk_u, N);
    k_kp<<<dim3(nkb), dim3(256), 0, stream>>>(dd_k, diag_k, mxk_u, kp, kp_part, N);
    k_kpsred<<<dim3(1), dim3(128), 0, stream>>>(kp_part, kp_sum, nkb);
    k_kvs<<<dim3(S3, NK, NH), dim3(64), 0, stream>>>(kp, gum, vbuf, kvs_part, kg_part, N);
    k_kvsred<<<dim3(300), dim3(256), 0, stream>>>(kvs_part, kvs);
    k_kgred<<<dim3(5), dim3(256), 0, stream>>>(kg_part, kg_sum);
    k_z<<<dim3((N+255)/256, 4), dim3(256), 0, stream>>>(qp, kvs, kg_sum, kp_sum,
                                                        den_node, z_out, N);
    k_wo<<<dim3((N+31)/32), dim3(256), 0, stream>>>(z_out, Wo, Wob, out, N);
    k_edge<<<dim3((E+255)/256), dim3(256), 0, stream>>>(ei, qp, kp, den_node, A, E);
}

// Round 2
// 1190.868 us; speedup vs baseline: 1.2548x; 1.2548x over previous
//
#include <hip/hip_runtime.h>
#include <math.h>

#define NH 4
#define ND 64
#define NC 128
#define NHD 256
#define NM 30
#define NK 10
#define EPSF 1e-6f
#define RATIO 0.18257418583505536f    // 1/sqrt(30)
#define QKSCALE 0.7071067811865476f   // inv_sqrt_tau(=2) * 64^{-1/4}(=0.353553)
#define S3 64                         // kvs reduction segments

__device__ __forceinline__ unsigned f2ord(float f){ unsigned b=__float_as_uint(f); return (b&0x80000000u)?~b:(b|0x80000000u); }
__device__ __forceinline__ float ord2f(unsigned u){ return __uint_as_float((u&0x80000000u)?(u&0x7fffffffu):~u); }
// round-to-nearest-even f32 -> bf16 (values are positive finite here)
__device__ __forceinline__ ushort f2bf(float f){ unsigned b=__float_as_uint(f); return (ushort)((b + 0x7fffu + ((b>>16)&1u))>>16); }
__device__ __forceinline__ float bf2f(ushort u){ return __uint_as_float(((unsigned)u)<<16); }

__global__ void k_init(unsigned* mxk_u){ if (threadIdx.x < NH) mxk_u[threadIdx.x] = 0u; }

// ---------------------------------------------------------------------------
// K1: fused QKV projection + q-features (qp) + dd_k/diag_k + v(bf16).
// 16 nodes/block.  Also writes bf16 qp into padded edge rows (qpe).
// ---------------------------------------------------------------------------
__global__ __launch_bounds__(256) void k_qkv(
    const float* __restrict__ z, const float* __restrict__ proj,
    const float* __restrict__ Wq, const float* __restrict__ bq,
    const float* __restrict__ Wk, const float* __restrict__ bk,
    const float* __restrict__ Wv, const float* __restrict__ bv,
    float* __restrict__ qp, ushort* __restrict__ qpe,
    float* __restrict__ dd_k, float* __restrict__ diag_k,
    ushort* __restrict__ v16, int N)
{
    const int NB = 16;
    __shared__ float zs[NB*NC];        // 8 KB
    __shared__ float xs[NB*8*65];      // 33.3 KB   row = nb*8 + qk*4 + h, stride 65 (bank-safe)
    __shared__ float proj_s[NM*65];    // 7.8 KB
    __shared__ float ddq_s[NB*120];    // 7.7 KB
    __shared__ float diagq_s[NB*4];
    int tid = threadIdx.x;
    int n0 = blockIdx.x * NB;

    for (int i = tid; i < NB*NC; i += 256) {
        int n = n0 + i / NC;
        zs[i] = (n < N) ? z[(size_t)n0*NC + i] : 0.f;
    }
    for (int i = tid; i < NM*ND; i += 256)
        proj_s[(i/ND)*65 + (i%ND)] = proj[i];
    __syncthreads();

    // qkv for output column `tid` over 16 nodes
    float accq[NB], acck[NB], accv[NB];
    #pragma unroll
    for (int nb=0;nb<NB;nb++){ accq[nb]=0.f; acck[nb]=0.f; accv[nb]=0.f; }
    float bqv = bq[tid], bkv = bk[tid], bvv = bv[tid];
    for (int c=0;c<NC;c++) {
        float wq = Wq[c*NHD+tid], wk = Wk[c*NHD+tid], wv = Wv[c*NHD+tid];
        #pragma unroll
        for (int nb=0;nb<NB;nb++) {
            float zc = zs[nb*NC+c];
            accq[nb] = fmaf(zc, wq, accq[nb]);
            acck[nb] = fmaf(zc, wk, acck[nb]);
            accv[nb] = fmaf(zc, wv, accv[nb]);
        }
    }
    int hcol = tid >> 6, dcol = tid & 63;
    for (int nb=0;nb<NB;nb++) {
        int n = n0+nb;
        if (n < N) v16[(size_t)n*NHD + tid] = f2bf(accv[nb] + bvv);
        xs[(nb*8 + hcol)*65 + dcol]     = (accq[nb] + bqv) * QKSCALE;
        xs[(nb*8 + 4 + hcol)*65 + dcol] = (acck[nb] + bkv) * QKSCALE;
    }
    __syncthreads();

    // dd dot products: 16 nodes x {q,k} x 4h x 30m = 3840 dots of length 64
    for (int i = tid; i < NB*240; i += 256) {
        int nb = i / 240, r = i % 240;
        int qk = r / 120, hm = r % 120;
        int hh = hm / 30, m = hm % 30;
        const float* xrow = &xs[(nb*8 + qk*4 + hh)*65];
        const float* prow = &proj_s[m*65];
        float s = 0.f;
        #pragma unroll
        for (int d=0; d<ND; d++) s = fmaf(xrow[d], prow[d], s);
        if (qk == 0) ddq_s[nb*120 + hm] = s;
        else { int n = n0+nb; if (n < N) dd_k[(size_t)hh*N*NM + (size_t)n*NM + m] = s; }
    }
    // diag = 0.5 * sum(x^2): 16 x 2 x 4 = 128 values
    if (tid < NB*8) {
        int nb = tid/8, r = tid%8, qk = r/4, hh = r%4;
        const float* xrow = &xs[(nb*8 + qk*4 + hh)*65];
        float s = 0.f;
        #pragma unroll
        for (int d=0; d<ND; d++) s = fmaf(xrow[d], xrow[d], s);
        s *= 0.5f;
        if (qk == 0) diagq_s[nb*4+hh] = s;
        else { int n = n0+nb; if (n < N) diag_k[n*4+hh] = s; }
    }
    __syncthreads();

    // qp = ratio*(exp(dd - diag - max_m dd) + eps)
    for (int i = tid; i < NB*120; i += 256) {
        int nb = i/120, hm = i%120, hh = hm/30;
        int n = n0+nb;
        if (n >= N) continue;
        float mx = -3.0e38f;
        #pragma unroll
        for (int j=0;j<NM;j++) mx = fmaxf(mx, ddq_s[nb*120 + hh*30 + j]);
        float val = RATIO * (__expf(ddq_s[nb*120+hm] - diagq_s[nb*4+hh] - mx) + EPSF);
        qp[(size_t)n*120 + hm] = val;
        qpe[(size_t)n*128 + hm] = f2bf(val);
    }
}

// ---------------------------------------------------------------------------
// K1.5: global max of dd_k per head
// ---------------------------------------------------------------------------
__global__ __launch_bounds__(256) void k_maxred(const float* __restrict__ dd_k,
                                                unsigned* __restrict__ mxk_u, int N)
{
    int hh = blockIdx.y;
    size_t len = (size_t)N*NM;
    const float* p = dd_k + (size_t)hh*len;
    float mx = -3.0e38f;
    for (size_t i = (size_t)blockIdx.x*256 + threadIdx.x; i < len; i += (size_t)gridDim.x*256)
        mx = fmaxf(mx, p[i]);
    for (int o=32;o>0;o>>=1) mx = fmaxf(mx, __shfl_down(mx, o));
    __shared__ float wmax[4];
    if ((threadIdx.x & 63) == 0) wmax[threadIdx.x >> 6] = mx;
    __syncthreads();
    if (threadIdx.x == 0) {
        mx = fmaxf(fmaxf(wmax[0],wmax[1]), fmaxf(wmax[2],wmax[3]));
        atomicMax(&mxk_u[hh], f2ord(mx));
    }
}

// ---------------------------------------------------------------------------
// K2: kp = ratio*(exp(dd_k - diag_k - mxk) + eps), bf16 copy (kpe), partial sums.
// 128 nodes per block.
// ---------------------------------------------------------------------------
__global__ __launch_bounds__(256) void k_kp(const float* __restrict__ dd_k,
    const float* __restrict__ diag_k, const unsigned* __restrict__ mxk_u,
    float* __restrict__ kp, ushort* __restrict__ kpe,
    float* __restrict__ kp_part, int N)
{
    __shared__ float psum[120];
    int tid = threadIdx.x;
    if (tid < 120) psum[tid] = 0.f;
    float mxk[NH];
    #pragma unroll
    for (int hh=0;hh<NH;hh++) mxk[hh] = ord2f(mxk_u[hh]);
    __syncthreads();
    int n0 = blockIdx.x * 128;
    for (int r = 0; r < 60; r++) {
        int idx = r*256 + tid;          // covers 128*120
        int nl = idx / 120, hm = idx % 120;
        int n = n0 + nl;
        if (n >= N) break;
        int hh = hm/30, m = hm%30;
        float val = RATIO * (__expf(dd_k[(size_t)hh*N*NM + (size_t)n*NM + m]
                                    - diag_k[n*4+hh] - mxk[hh]) + EPSF);
        kp[(size_t)n*120 + hm] = val;
        kpe[(size_t)n*128 + hm] = f2bf(val);
        atomicAdd(&psum[hm], val);
    }
    __syncthreads();
    if (tid < 120) kp_part[blockIdx.x*120 + tid] = psum[tid];
}

__global__ void k_kpsred(const float* __restrict__ kp_part, float* __restrict__ kp_sum, int nblk){
    int t = threadIdx.x;
    if (t < 120) {
        float s = 0.f;
        for (int b=0;b<nblk;b++) s += kp_part[b*120+t];
        kp_sum[t] = s;
    }
}

// ---------------------------------------------------------------------------
// K3: kvs partials.  block = (seg, k, h), 64 threads (thread = d).  v is bf16.
// ---------------------------------------------------------------------------
__global__ __launch_bounds__(64) void k_kvs(const float* __restrict__ kp,
    const float* __restrict__ gum, const ushort* __restrict__ v16,
    float* __restrict__ kvs_part, float* __restrict__ kg_part, int N)
{
    int seg = blockIdx.x, k = blockIdx.y, hh = blockIdx.z;
    int tid = threadIdx.x;
    int ns = (N + S3 - 1)/S3;
    int n0 = seg*ns, n1 = min(N, n0+ns);
    __shared__ float egs[64];
    __shared__ float kpeg[64*32];
    float acc[NM];
    #pragma unroll
    for (int m=0;m<NM;m++) acc[m]=0.f;
    float acckg = 0.f;
    for (int nc = n0; nc < n1; nc += 64) {
        int cn = min(64, n1-nc);
        __syncthreads();
        if (tid < cn) egs[tid] = __expf(gum[(size_t)(nc+tid)*(NH*NK) + hh*NK + k]);
        __syncthreads();
        for (int i = tid; i < cn*32; i += 64) {
            int nl = i >> 5, mm = i & 31;
            kpeg[i] = (mm < NM) ? kp[(size_t)(nc+nl)*120 + hh*30 + mm] * egs[nl] : 0.f;
        }
        __syncthreads();
        for (int nl = 0; nl < cn; nl++) {
            float vd = bf2f(v16[(size_t)(nc+nl)*NHD + hh*64 + tid]);
            const float* kr = &kpeg[nl*32];
            #pragma unroll
            for (int m=0;m<NM;m++) acc[m] = fmaf(kr[m], vd, acc[m]);
            if (tid < NM) acckg += kr[tid];
        }
    }
    size_t base = (size_t)(hh*NK + k)*S3 + seg;
    for (int m=0;m<NM;m++) kvs_part[base*1920 + m*64 + tid] = acc[m];
    if (tid < NM) kg_part[base*30 + tid] = acckg;
}

__global__ void k_kvsred(const float* __restrict__ kvs_part, float* __restrict__ kvs){
    int o = blockIdx.x*256 + threadIdx.x;       // 76800 outputs
    if (o >= NH*NK*1920) return;
    int hk = o / 1920, md = o % 1920;
    float s = 0.f;
    for (int sg=0; sg<S3; sg++) s += kvs_part[((size_t)hk*S3 + sg)*1920 + md];
    kvs[o] = s;
}
__global__ void k_kgred(const float* __restrict__ kg_part, float* __restrict__ kg_sum){
    int o = blockIdx.x*256 + threadIdx.x;       // 1200 outputs
    if (o >= NH*NK*30) return;
    int hk = o/30, m = o%30;
    float s = 0.f;
    for (int sg=0; sg<S3; sg++) s += kg_part[((size_t)hk*S3+sg)*30 + m];
    kg_sum[o] = s;
}

// ---------------------------------------------------------------------------
// K5: per-node z_out (mean_k z_num/z_den); den written into qpe row tail.
// blockIdx.y = head.  kvs[h] staged in LDS in two k-halves (38.4 KB).
// ---------------------------------------------------------------------------
__global__ __launch_bounds__(256) void k_z(const float* __restrict__ qp,
    const float* __restrict__ kvs, const float* __restrict__ kg_sum,
    const float* __restrict__ kp_sum, ushort* __restrict__ qpe,
    float* __restrict__ z_out, int N)
{
    __shared__ float kvs_s[5*30*64];
    __shared__ float kg_s[NK*30];
    __shared__ float kps_s[30];
    int tid = threadIdx.x;
    int hh = blockIdx.y;
    int n = blockIdx.x*256 + tid;
    bool valid = (n < N);

    for (int i=tid;i<300;i+=256) kg_s[i] = kg_sum[hh*300+i];
    if (tid<30) kps_s[tid] = kp_sum[hh*30+tid];
    for (int i=tid;i<9600;i+=256) kvs_s[i] = kvs[(size_t)hh*19200 + i];
    __syncthreads();

    float qv[NM]; float scale[NK];
    if (valid) {
        const float2* q2 = (const float2*)(qp + (size_t)n*120 + hh*30);
        #pragma unroll
        for (int j=0;j<15;j++){ float2 t = q2[j]; qv[2*j]=t.x; qv[2*j+1]=t.y; }
        float dn = 0.f;
        #pragma unroll
        for (int m=0;m<NM;m++) dn = fmaf(qv[m], kps_s[m], dn);
        ((float*)qpe)[(size_t)n*64 + 60 + hh] = dn;   // den packed at row tail
        #pragma unroll
        for (int k=0;k<NK;k++){
            float s=0.f;
            #pragma unroll
            for (int m=0;m<NM;m++) s = fmaf(qv[m], kg_s[k*30+m], s);
            scale[k] = (1.0f/NK) / s;
        }
    }
    float4 zacc[16];
    #pragma unroll
    for (int i=0;i<16;i++) zacc[i] = make_float4(0.f,0.f,0.f,0.f);

    if (valid) {
        for (int k=0;k<5;k++)
            for (int m=0;m<NM;m++){
                float w = qv[m]*scale[k];
                const float4* kr = (const float4*)&kvs_s[(k*30+m)*64];
                #pragma unroll
                for (int d4=0; d4<16; d4++){
                    float4 kv = kr[d4];
                    zacc[d4].x = fmaf(w, kv.x, zacc[d4].x);
                    zacc[d4].y = fmaf(w, kv.y, zacc[d4].y);
                    zacc[d4].z = fmaf(w, kv.z, zacc[d4].z);
                    zacc[d4].w = fmaf(w, kv.w, zacc[d4].w);
                }
            }
    }
    __syncthreads();
    for (int i=tid;i<9600;i+=256) kvs_s[i] = kvs[(size_t)hh*19200 + 9600 + i];
    __syncthreads();
    if (valid) {
        for (int k=0;k<5;k++)
            for (int m=0;m<NM;m++){
                float w = qv[m]*scale[5+k];
                const float4* kr = (const float4*)&kvs_s[(k*30+m)*64];
                #pragma unroll
                for (int d4=0; d4<16; d4++){
                    float4 kv = kr[d4];
                    zacc[d4].x = fmaf(w, kv.x, zacc[d4].x);
                    zacc[d4].y = fmaf(w, kv.y, zacc[d4].y);
                    zacc[d4].z = fmaf(w, kv.z, zacc[d4].z);
                    zacc[d4].w = fmaf(w, kv.w, zacc[d4].w);
                }
            }
        float4* zo = (float4*)(z_out + (size_t)n*NHD + hh*64);
        #pragma unroll
        for (int d4=0;d4<16;d4++) zo[d4] = zacc[d4];
    }
}

// ---------------------------------------------------------------------------
// K6: out = z_out @ Wo + b.  32 nodes/block, Wo + z staged by j-halves.
// ---------------------------------------------------------------------------
__global__ __launch_bounds__(256) void k_wo(const float* __restrict__ z_out,
    const float* __restrict__ Wo, const float* __restrict__ Wob,
    float* __restrict__ out, int N)
{
    __shared__ float wo_s[128*64];   // 32 KB
    __shared__ float z_s[32*128];    // 16 KB
    int tid = threadIdx.x;
    int n0 = blockIdx.x*32;
    int col4 = tid & 15, nl = tid >> 4;   // nodes nl and nl+16
    float4 acc0 = make_float4(0.f,0.f,0.f,0.f), acc1 = acc0;
    for (int jh=0; jh<2; jh++){
        __syncthreads();
        for (int i=tid;i<128*64;i+=256) wo_s[i] = Wo[jh*128*64 + i];
        for (int i=tid;i<32*128;i+=256){
            int nn = n0 + i/128;
            z_s[i] = (nn<N)? z_out[(size_t)nn*NHD + jh*128 + (i%128)] : 0.f;
        }
        __syncthreads();
        for (int j=0;j<128;j++){
            float4 w4 = *(const float4*)&wo_s[j*64 + col4*4];
            float zv0 = z_s[nl*128 + j];
            float zv1 = z_s[(nl+16)*128 + j];
            acc0.x = fmaf(zv0, w4.x, acc0.x); acc0.y = fmaf(zv0, w4.y, acc0.y);
            acc0.z = fmaf(zv0, w4.z, acc0.z); acc0.w = fmaf(zv0, w4.w, acc0.w);
            acc1.x = fmaf(zv1, w4.x, acc1.x); acc1.y = fmaf(zv1, w4.y, acc1.y);
            acc1.z = fmaf(zv1, w4.z, acc1.z); acc1.w = fmaf(zv1, w4.w, acc1.w);
        }
    }
    float4 bv = *(const float4*)&Wob[col4*4];
    int nA = n0+nl, nB = n0+nl+16;
    if (nA < N) {
        float4 r = make_float4(acc0.x+bv.x, acc0.y+bv.y, acc0.z+bv.z, acc0.w+bv.w);
        *(float4*)(out + (size_t)nA*ND + col4*4) = r;
    }
    if (nB < N) {
        float4 r = make_float4(acc1.x+bv.x, acc1.y+bv.y, acc1.z+bv.z, acc1.w+bv.w);
        *(float4*)(out + (size_t)nB*ND + col4*4) = r;
    }
}

// ---------------------------------------------------------------------------
// K7: edge attention weights.  one thread per edge; bf16 256B-aligned rows;
// den packed in qpe row tail (same cache lines as qp row).
// ---------------------------------------------------------------------------
__global__ __launch_bounds__(256) void k_edge(const int* __restrict__ ei,
    const ushort* __restrict__ qpe, const ushort* __restrict__ kpe,
    float* __restrict__ A, int E)
{
    int e = blockIdx.x*256 + threadIdx.x;
    if (e >= E) return;
    int s = ei[e], t = ei[E + e];
    const uint4* rq = (const uint4*)(qpe + (size_t)t*128);
    const uint4* rk = (const uint4*)(kpe + (size_t)s*128);
    float num[NH] = {0.f,0.f,0.f,0.f};
    #define ACC2(au,bu,idx0) { \
        float a0=__uint_as_float((au)<<16),        b0=__uint_as_float((bu)<<16); \
        float a1=__uint_as_float((au)&0xffff0000u),b1=__uint_as_float((bu)&0xffff0000u); \
        num[(idx0)/30]     = fmaf(a0,b0,num[(idx0)/30]); \
        num[((idx0)+1)/30] = fmaf(a1,b1,num[((idx0)+1)/30]); }
    #pragma unroll
    for (int j=0;j<15;j++){
        uint4 a = rq[j], b = rk[j];
        ACC2(a.x, b.x, j*8+0)
        ACC2(a.y, b.y, j*8+2)
        ACC2(a.z, b.z, j*8+4)
        ACC2(a.w, b.w, j*8+6)
    }
    #undef ACC2
    float4 dn = *(const float4*)((const float*)qpe + (size_t)t*64 + 60);
    float4 res = make_float4(num[0]/dn.x, num[1]/dn.y, num[2]/dn.z, num[3]/dn.w);
    *(float4*)(A + (size_t)e*4) = res;
}

// ---------------------------------------------------------------------------
extern "C" void kernel_launch(void* const* d_in, const int* in_sizes, int n_in,
                              void* d_out, int out_size, void* d_ws, size_t ws_size,
                              hipStream_t stream)
{
    const float* z    = (const float*)d_in[0];
    const int*   ei   = (const int*)d_in[1];
    const float* gum  = (const float*)d_in[2];
    const float* proj = (const float*)d_in[3];
    const float* Wq   = (const float*)d_in[4];
    const float* bq   = (const float*)d_in[5];
    const float* Wk   = (const float*)d_in[6];
    const float* bk   = (const float*)d_in[7];
    const float* Wv   = (const float*)d_in[8];
    const float* bv   = (const float*)d_in[9];
    const float* Wo   = (const float*)d_in[10];
    const float* Wob  = (const float*)d_in[11];
    int N = in_sizes[0] / NC;
    int E = in_sizes[1] / 2;

    float* ws = (float*)d_ws;
    size_t o = 0;
    float* qp       = ws + o; o += (size_t)N*120;
    float* kp       = ws + o; o += (size_t)N*120;
    float* vbuf     = ws + o; float* z_out = vbuf;       o += (size_t)N*NHD;   // v(bf16) and z_out share (disjoint lifetimes)
    float* dd_k     = ws + o; float* kvs_part = dd_k;    o += (size_t)NH*N*NM; // kvs_part reuses dd_k
    float* diag_k   = ws + o; o += (size_t)N*4;
    unsigned* mxk_u = (unsigned*)(ws + o); o += 4;
    int nkb = (N+127)/128;
    float* kp_part  = ws + o; o += (size_t)nkb*120;
    float* kp_sum   = ws + o; o += 120;
    float* kg_part  = ws + o; o += (size_t)NH*NK*S3*30;
    float* kvs      = ws + o; o += (size_t)NH*NK*1920;
    float* kg_sum   = ws + o; o += (size_t)NH*NK*30;
    ushort* qpe     = (ushort*)(ws + o); o += (size_t)N*64;   // 120 bf16 + 4 f32 den = 256B rows
    ushort* kpe     = (ushort*)(ws + o); o += (size_t)N*64;   // 120 bf16, 256B rows
    ushort* v16     = (ushort*)vbuf;

    float* out = (float*)d_out;
    float* A   = out + (size_t)N*ND;

    k_init<<<dim3(1), dim3(64), 0, stream>>>(mxk_u);
    k_qkv<<<dim3((N+15)/16), dim3(256), 0, stream>>>(z, proj, Wq, bq, Wk, bk, Wv, bv,
                                                     qp, qpe, dd_k, diag_k, v16, N);
    k_maxred<<<dim3(48,4), dim3(256), 0, stream>>>(dd_k, mxk_u, N);
    k_kp<<<dim3(nkb), dim3(256), 0, stream>>>(dd_k, diag_k, mxk_u, kp, kpe, kp_part, N);
    k_kpsred<<<dim3(1), dim3(128), 0, stream>>>(kp_part, kp_sum, nkb);
    k_kvs<<<dim3(S3, NK, NH), dim3(64), 0, stream>>>(kp, gum, v16, kvs_part, kg_part, N);
    k_kvsred<<<dim3(300), dim3(256), 0, stream>>>(kvs_part, kvs);
    k_kgred<<<dim3(5), dim3(256), 0, stream>>>(kg_part, kg_sum);
    k_z<<<dim3((N+255)/256, 4), dim3(256), 0, stream>>>(qp, kvs, kg_sum, kp_sum,
                                                        qpe, z_out, N);
    k_wo<<<dim3((N+31)/32), dim3(256), 0, stream>>>(z_out, Wo, Wob, out, N);
    k_edge<<<dim3((E+255)/256), dim3(256), 0, stream>>>(ei, qpe, kpe, A, E);
}

// Round 3
// 1148.318 us; speedup vs baseline: 1.3013x; 1.0371x over previous
//
#include <hip/hip_runtime.h>
#include <math.h>

#define NH 4
#define ND 64
#define NC 128
#define NHD 256
#define NM 30
#define NK 10
#define EPSF 1e-6f
#define RATIO 0.18257418583505536f    // 1/sqrt(30)
#define QKSCALE 0.7071067811865476f   // inv_sqrt_tau(=2) * 64^{-1/4}(=0.353553)
#define S3 64                         // kvs reduction segments

typedef float f32x4 __attribute__((ext_vector_type(4)));
typedef short s16x8 __attribute__((ext_vector_type(8)));

__device__ __forceinline__ unsigned f2ord(float f){ unsigned b=__float_as_uint(f); return (b&0x80000000u)?~b:(b|0x80000000u); }
__device__ __forceinline__ float ord2f(unsigned u){ return __uint_as_float((u&0x80000000u)?(u&0x7fffffffu):~u); }
// round-to-nearest-even f32 -> bf16 (finite values)
__device__ __forceinline__ ushort f2bf(float f){ unsigned b=__float_as_uint(f); return (ushort)((b + 0x7fffu + ((b>>16)&1u))>>16); }
__device__ __forceinline__ float bf2f(ushort u){ return __uint_as_float(((unsigned)u)<<16); }

__global__ void k_init(unsigned* mxk_u){ if (threadIdx.x < NH) mxk_u[threadIdx.x] = 0u; }

// ---------------------------------------------------------------------------
// K0: prep W (q|k|v concat, 768 cols) into MFMA B-fragment layout, bf16 hi/lo.
// Layout: [tile=48][ks=4][lane=64][j=8]: col = tile*16+(lane&15),
// k = ks*32+(lane>>4)*8+j.  One thread per (tile,ks,lane).
// ---------------------------------------------------------------------------
__global__ __launch_bounds__(256) void k_wprep(const float* __restrict__ Wq,
    const float* __restrict__ Wk, const float* __restrict__ Wv,
    ushort* __restrict__ Wt_h, ushort* __restrict__ Wt_l)
{
    int idx = blockIdx.x*256 + threadIdx.x;   // 48*4*64 = 12288
    if (idx >= 48*4*64) return;
    int lane = idx & 63, ks = (idx>>6)&3, tile = idx>>8;
    int c = tile*16 + (lane&15);
    int k0 = ks*32 + (lane>>4)*8;
    const float* W; int cc;
    if (c < 256)      { W = Wq; cc = c; }
    else if (c < 512) { W = Wk; cc = c-256; }
    else              { W = Wv; cc = c-512; }
    #pragma unroll
    for (int j=0;j<8;j++){
        float w = W[(size_t)(k0+j)*NHD + cc];
        ushort h = f2bf(w);
        Wt_h[(size_t)idx*8+j] = h;
        Wt_l[(size_t)idx*8+j] = f2bf(w - bf2f(h));
    }
}

// ---------------------------------------------------------------------------
// K1: QKV projection via 3-pass split-bf16 MFMA + q-features + dd_k/diag_k + v16.
// 16 nodes/block, 4 waves; wave w owns col tiles [w*12, w*12+12).
// ---------------------------------------------------------------------------
__global__ __launch_bounds__(256) void k_qkv(
    const float* __restrict__ z,
    const ushort* __restrict__ Wt_h, const ushort* __restrict__ Wt_l,
    const float* __restrict__ bq, const float* __restrict__ bk,
    const float* __restrict__ bv, const float* __restrict__ proj,
    float* __restrict__ qp, ushort* __restrict__ qpe,
    float* __restrict__ dd_k, float* __restrict__ diag_k,
    ushort* __restrict__ v16, int N)
{
    const int NB = 16;
    __shared__ float xs[NB*8*65];      // 33.3 KB  row = nb*8 + qk*4 + h
    __shared__ float buf2[4096];       // 16 KB: v staging, then proj_s/ddq_s/diagq_s
    int tid = threadIdx.x;
    int n0 = blockIdx.x * NB;
    int w = tid >> 6, lane = tid & 63;
    int arow = lane & 15, kgrp = lane >> 4;

    // ---- A fragments (z rows) from global, split into bf16 hi/lo ----
    int nn = n0 + arow; if (nn > N-1) nn = N-1;
    const float* zrow = z + (size_t)nn*NC;
    s16x8 ah[4], al[4];
    #pragma unroll
    for (int ks=0;ks<4;ks++){
        f32x4 f0 = *(const f32x4*)(zrow + ks*32 + kgrp*8);
        f32x4 f1 = *(const f32x4*)(zrow + ks*32 + kgrp*8 + 4);
        #pragma unroll
        for (int j=0;j<4;j++){
            float v0 = f0[j]; ushort h0 = f2bf(v0);
            ah[ks][j]   = (short)h0; al[ks][j]   = (short)f2bf(v0 - bf2f(h0));
            float v1 = f1[j]; ushort h1 = f2bf(v1);
            ah[ks][4+j] = (short)h1; al[ks][4+j] = (short)f2bf(v1 - bf2f(h1));
        }
    }

    // ---- MFMA over 12 col-tiles ----
    const uint4* WH = (const uint4*)Wt_h;
    const uint4* WL = (const uint4*)Wt_l;
    for (int nt=0; nt<12; nt++){
        int tile = w*12 + nt;
        f32x4 acc = {0.f,0.f,0.f,0.f};
        #pragma unroll
        for (int ks=0;ks<4;ks++){
            uint4 bhu = WH[(size_t)(tile*4+ks)*64 + lane];
            uint4 blu = WL[(size_t)(tile*4+ks)*64 + lane];
            s16x8 bh = __builtin_bit_cast(s16x8, bhu);
            s16x8 bl = __builtin_bit_cast(s16x8, blu);
            acc = __builtin_amdgcn_mfma_f32_16x16x32_bf16(ah[ks], bl, acc, 0,0,0);
            acc = __builtin_amdgcn_mfma_f32_16x16x32_bf16(al[ks], bh, acc, 0,0,0);
            acc = __builtin_amdgcn_mfma_f32_16x16x32_bf16(ah[ks], bh, acc, 0,0,0);
        }
        // epilogue: C layout col=lane&15, row=(lane>>4)*4+i   (m89-verified)
        int tb = tile*16;
        int c  = tb + (lane&15);
        if (tb < 512) {
            int qk = c >> 8, ccc = c & 255;
            float bias = (qk==0) ? bq[ccc] : bk[ccc];
            int hh = ccc>>6, d = ccc&63;
            float* dst = &xs[(qk*4+hh)*65 + d];
            #pragma unroll
            for (int i=0;i<4;i++){
                int r = kgrp*4 + i;
                dst[r*520] = (acc[i] + bias) * QKSCALE;
            }
        } else {
            int cv = c - 512;
            float bias = bv[cv];
            #pragma unroll
            for (int i=0;i<4;i++){
                int r = kgrp*4 + i;
                buf2[r*256 + cv] = acc[i] + bias;
            }
        }
    }
    __syncthreads();

    // ---- v16 store (coalesced bf16) ----
    #pragma unroll
    for (int it=0; it<16; it++){
        int i = it*256 + tid;
        int n = n0 + (i>>8);
        if (n < N) v16[(size_t)n*NHD + (i&255)] = f2bf(buf2[i]);
    }
    __syncthreads();

    // ---- phase 2 buffers overlay buf2 ----
    float* proj_s  = buf2;               // 30*65 = 1950
    float* ddq_s   = buf2 + 1952;        // 16*120 = 1920
    float* diagq_s = buf2 + 1952 + 1920; // 64
    for (int i = tid; i < NM*ND; i += 256)
        proj_s[(i/ND)*65 + (i%ND)] = proj[i];
    __syncthreads();

    // dd dot products: 16 nodes x {q,k} x 4h x 30m
    for (int i = tid; i < NB*240; i += 256) {
        int nb = i / 240, r = i % 240;
        int qk = r / 120, hm = r % 120;
        int hh = hm / 30, m = hm % 30;
        const float* xrow = &xs[(nb*8 + qk*4 + hh)*65];
        const float* prow = &proj_s[m*65];
        float s = 0.f;
        #pragma unroll
        for (int d=0; d<ND; d++) s = fmaf(xrow[d], prow[d], s);
        if (qk == 0) ddq_s[nb*120 + hm] = s;
        else { int n = n0+nb; if (n < N) dd_k[(size_t)hh*N*NM + (size_t)n*NM + m] = s; }
    }
    // diag = 0.5 * sum(x^2)
    if (tid < NB*8) {
        int nb = tid/8, r = tid%8, qk = r/4, hh = r%4;
        const float* xrow = &xs[(nb*8 + qk*4 + hh)*65];
        float s = 0.f;
        #pragma unroll
        for (int d=0; d<ND; d++) s = fmaf(xrow[d], xrow[d], s);
        s *= 0.5f;
        if (qk == 0) diagq_s[nb*4+hh] = s;
        else { int n = n0+nb; if (n < N) diag_k[n*4+hh] = s; }
    }
    __syncthreads();

    // qp = ratio*(exp(dd - diag - max_m dd) + eps)
    for (int i = tid; i < NB*120; i += 256) {
        int nb = i/120, hm = i%120, hh = hm/30;
        int n = n0+nb;
        if (n >= N) continue;
        float mx = -3.0e38f;
        #pragma unroll
        for (int j=0;j<NM;j++) mx = fmaxf(mx, ddq_s[nb*120 + hh*30 + j]);
        float val = RATIO * (__expf(ddq_s[nb*120+hm] - diagq_s[nb*4+hh] - mx) + EPSF);
        qp[(size_t)n*120 + hm] = val;
        qpe[(size_t)n*128 + hm] = f2bf(val);
    }
}

// ---------------------------------------------------------------------------
// K1.5: global max of dd_k per head
// ---------------------------------------------------------------------------
__global__ __launch_bounds__(256) void k_maxred(const float* __restrict__ dd_k,
                                                unsigned* __restrict__ mxk_u, int N)
{
    int hh = blockIdx.y;
    size_t len = (size_t)N*NM;
    const float* p = dd_k + (size_t)hh*len;
    float mx = -3.0e38f;
    for (size_t i = (size_t)blockIdx.x*256 + threadIdx.x; i < len; i += (size_t)gridDim.x*256)
        mx = fmaxf(mx, p[i]);
    for (int o=32;o>0;o>>=1) mx = fmaxf(mx, __shfl_down(mx, o));
    __shared__ float wmax[4];
    if ((threadIdx.x & 63) == 0) wmax[threadIdx.x >> 6] = mx;
    __syncthreads();
    if (threadIdx.x == 0) {
        mx = fmaxf(fmaxf(wmax[0],wmax[1]), fmaxf(wmax[2],wmax[3]));
        atomicMax(&mxk_u[hh], f2ord(mx));
    }
}

// ---------------------------------------------------------------------------
// K2: kp = ratio*(exp(dd_k - diag_k - mxk) + eps), bf16 copy (kpe), partial sums.
// ---------------------------------------------------------------------------
__global__ __launch_bounds__(256) void k_kp(const float* __restrict__ dd_k,
    const float* __restrict__ diag_k, const unsigned* __restrict__ mxk_u,
    float* __restrict__ kp, ushort* __restrict__ kpe,
    float* __restrict__ kp_part, int N)
{
    __shared__ float psum[120];
    int tid = threadIdx.x;
    if (tid < 120) psum[tid] = 0.f;
    float mxk[NH];
    #pragma unroll
    for (int hh=0;hh<NH;hh++) mxk[hh] = ord2f(mxk_u[hh]);
    __syncthreads();
    int n0 = blockIdx.x * 128;
    for (int r = 0; r < 60; r++) {
        int idx = r*256 + tid;          // covers 128*120
        int nl = idx / 120, hm = idx % 120;
        int n = n0 + nl;
        if (n >= N) break;
        int hh = hm/30, m = hm%30;
        float val = RATIO * (__expf(dd_k[(size_t)hh*N*NM + (size_t)n*NM + m]
                                    - diag_k[n*4+hh] - mxk[hh]) + EPSF);
        kp[(size_t)n*120 + hm] = val;
        kpe[(size_t)n*128 + hm] = f2bf(val);
        atomicAdd(&psum[hm], val);
    }
    __syncthreads();
    if (tid < 120) kp_part[blockIdx.x*120 + tid] = psum[tid];
}

__global__ void k_kpsred(const float* __restrict__ kp_part, float* __restrict__ kp_sum, int nblk){
    int t = threadIdx.x;
    if (t < 120) {
        float s = 0.f;
        for (int b=0;b<nblk;b++) s += kp_part[b*120+t];
        kp_sum[t] = s;
    }
}

// ---------------------------------------------------------------------------
// K3: kvs partials.  block = (seg, k, h), 64 threads (thread = d).  v is bf16.
// kpeg read as float4 (8 b128 broadcasts/node instead of 30 b32).
// ---------------------------------------------------------------------------
__global__ __launch_bounds__(64) void k_kvs(const float* __restrict__ kp,
    const float* __restrict__ gum, const ushort* __restrict__ v16,
    float* __restrict__ kvs_part, float* __restrict__ kg_part, int N)
{
    int seg = blockIdx.x, k = blockIdx.y, hh = blockIdx.z;
    int tid = threadIdx.x;
    int ns = (N + S3 - 1)/S3;
    int n0 = seg*ns, n1 = min(N, n0+ns);
    __shared__ float egs[64];
    __shared__ float kpeg[64*32];
    float acc[32];
    #pragma unroll
    for (int m=0;m<32;m++) acc[m]=0.f;
    float acckg = 0.f;
    for (int nc = n0; nc < n1; nc += 64) {
        int cn = min(64, n1-nc);
        __syncthreads();
        if (tid < cn) egs[tid] = __expf(gum[(size_t)(nc+tid)*(NH*NK) + hh*NK + k]);
        __syncthreads();
        for (int i = tid; i < cn*32; i += 64) {
            int nl = i >> 5, mm = i & 31;
            kpeg[i] = (mm < NM) ? kp[(size_t)(nc+nl)*120 + hh*30 + mm] * egs[nl] : 0.f;
        }
        __syncthreads();
        for (int nl = 0; nl < cn; nl++) {
            float vd = bf2f(v16[(size_t)(nc+nl)*NHD + hh*64 + tid]);
            const float4* kr = (const float4*)&kpeg[nl*32];
            #pragma unroll
            for (int m4=0;m4<8;m4++){
                float4 kk = kr[m4];
                acc[m4*4+0] = fmaf(kk.x, vd, acc[m4*4+0]);
                acc[m4*4+1] = fmaf(kk.y, vd, acc[m4*4+1]);
                acc[m4*4+2] = fmaf(kk.z, vd, acc[m4*4+2]);
                acc[m4*4+3] = fmaf(kk.w, vd, acc[m4*4+3]);
            }
            if (tid < NM) acckg += kpeg[nl*32+tid];
        }
    }
    size_t base = (size_t)(hh*NK + k)*S3 + seg;
    for (int m=0;m<NM;m++) kvs_part[base*1920 + m*64 + tid] = acc[m];
    if (tid < NM) kg_part[base*30 + tid] = acckg;
}

__global__ void k_kvsred(const float* __restrict__ kvs_part, float* __restrict__ kvs){
    int o = blockIdx.x*256 + threadIdx.x;       // 76800 outputs
    if (o >= NH*NK*1920) return;
    int hk = o / 1920, md = o % 1920;
    float s = 0.f;
    for (int sg=0; sg<S3; sg++) s += kvs_part[((size_t)hk*S3 + sg)*1920 + md];
    kvs[o] = s;
}
__global__ void k_kgred(const float* __restrict__ kg_part, float* __restrict__ kg_sum){
    int o = blockIdx.x*256 + threadIdx.x;       // 1200 outputs
    if (o >= NH*NK*30) return;
    int hk = o/30, m = o%30;
    float s = 0.f;
    for (int sg=0; sg<S3; sg++) s += kg_part[((size_t)hk*S3+sg)*30 + m];
    kg_sum[o] = s;
}

// ---------------------------------------------------------------------------
// K5: per-node z_out (mean_k z_num/z_den); den written into qpe row tail.
// ---------------------------------------------------------------------------
__global__ __launch_bounds__(256) void k_z(const float* __restrict__ qp,
    const float* __restrict__ kvs, const float* __restrict__ kg_sum,
    const float* __restrict__ kp_sum, ushort* __restrict__ qpe,
    float* __restrict__ z_out, int N)
{
    __shared__ float kvs_s[5*30*64];
    __shared__ float kg_s[NK*30];
    __shared__ float kps_s[30];
    int tid = threadIdx.x;
    int hh = blockIdx.y;
    int n = blockIdx.x*256 + tid;
    bool valid = (n < N);

    for (int i=tid;i<300;i+=256) kg_s[i] = kg_sum[hh*300+i];
    if (tid<30) kps_s[tid] = kp_sum[hh*30+tid];
    for (int i=tid;i<9600;i+=256) kvs_s[i] = kvs[(size_t)hh*19200 + i];
    __syncthreads();

    float qv[NM]; float scale[NK];
    if (valid) {
        const float2* q2 = (const float2*)(qp + (size_t)n*120 + hh*30);
        #pragma unroll
        for (int j=0;j<15;j++){ float2 t = q2[j]; qv[2*j]=t.x; qv[2*j+1]=t.y; }
        float dn = 0.f;
        #pragma unroll
        for (int m=0;m<NM;m++) dn = fmaf(qv[m], kps_s[m], dn);
        ((float*)qpe)[(size_t)n*64 + 60 + hh] = dn;   // den packed at row tail
        #pragma unroll
        for (int k=0;k<NK;k++){
            float s=0.f;
            #pragma unroll
            for (int m=0;m<NM;m++) s = fmaf(qv[m], kg_s[k*30+m], s);
            scale[k] = (1.0f/NK) / s;
        }
    }
    float4 zacc[16];
    #pragma unroll
    for (int i=0;i<16;i++) zacc[i] = make_float4(0.f,0.f,0.f,0.f);

    if (valid) {
        for (int k=0;k<5;k++)
            for (int m=0;m<NM;m++){
                float w = qv[m]*scale[k];
                const float4* kr = (const float4*)&kvs_s[(k*30+m)*64];
                #pragma unroll
                for (int d4=0; d4<16; d4++){
                    float4 kv = kr[d4];
                    zacc[d4].x = fmaf(w, kv.x, zacc[d4].x);
                    zacc[d4].y = fmaf(w, kv.y, zacc[d4].y);
                    zacc[d4].z = fmaf(w, kv.z, zacc[d4].z);
                    zacc[d4].w = fmaf(w, kv.w, zacc[d4].w);
                }
            }
    }
    __syncthreads();
    for (int i=tid;i<9600;i+=256) kvs_s[i] = kvs[(size_t)hh*19200 + 9600 + i];
    __syncthreads();
    if (valid) {
        for (int k=0;k<5;k++)
            for (int m=0;m<NM;m++){
                float w = qv[m]*scale[5+k];
                const float4* kr = (const float4*)&kvs_s[(k*30+m)*64];
                #pragma unroll
                for (int d4=0; d4<16; d4++){
                    float4 kv = kr[d4];
                    zacc[d4].x = fmaf(w, kv.x, zacc[d4].x);
                    zacc[d4].y = fmaf(w, kv.y, zacc[d4].y);
                    zacc[d4].z = fmaf(w, kv.z, zacc[d4].z);
                    zacc[d4].w = fmaf(w, kv.w, zacc[d4].w);
                }
            }
        float4* zo = (float4*)(z_out + (size_t)n*NHD + hh*64);
        #pragma unroll
        for (int d4=0;d4<16;d4++) zo[d4] = zacc[d4];
    }
}

// ---------------------------------------------------------------------------
// K6: out = z_out @ Wo + b.
// ---------------------------------------------------------------------------
__global__ __launch_bounds__(256) void k_wo(const float* __restrict__ z_out,
    const float* __restrict__ Wo, const float* __restrict__ Wob,
    float* __restrict__ out, int N)
{
    __shared__ float wo_s[128*64];   // 32 KB
    __shared__ float z_s[32*128];    // 16 KB
    int tid = threadIdx.x;
    int n0 = blockIdx.x*32;
    int col4 = tid & 15, nl = tid >> 4;
    float4 acc0 = make_float4(0.f,0.f,0.f,0.f), acc1 = acc0;
    for (int jh=0; jh<2; jh++){
        __syncthreads();
        for (int i=tid;i<128*64;i+=256) wo_s[i] = Wo[jh*128*64 + i];
        for (int i=tid;i<32*128;i+=256){
            int nn = n0 + i/128;
            z_s[i] = (nn<N)? z_out[(size_t)nn*NHD + jh*128 + (i%128)] : 0.f;
        }
        __syncthreads();
        for (int j=0;j<128;j++){
            float4 w4 = *(const float4*)&wo_s[j*64 + col4*4];
            float zv0 = z_s[nl*128 + j];
            float zv1 = z_s[(nl+16)*128 + j];
            acc0.x = fmaf(zv0, w4.x, acc0.x); acc0.y = fmaf(zv0, w4.y, acc0.y);
            acc0.z = fmaf(zv0, w4.z, acc0.z); acc0.w = fmaf(zv0, w4.w, acc0.w);
            acc1.x = fmaf(zv1, w4.x, acc1.x); acc1.y = fmaf(zv1, w4.y, acc1.y);
            acc1.z = fmaf(zv1, w4.z, acc1.z); acc1.w = fmaf(zv1, w4.w, acc1.w);
        }
    }
    float4 bvv = *(const float4*)&Wob[col4*4];
    int nA = n0+nl, nB = n0+nl+16;
    if (nA < N) {
        float4 r = make_float4(acc0.x+bvv.x, acc0.y+bvv.y, acc0.z+bvv.z, acc0.w+bvv.w);
        *(float4*)(out + (size_t)nA*ND + col4*4) = r;
    }
    if (nB < N) {
        float4 r = make_float4(acc1.x+bvv.x, acc1.y+bvv.y, acc1.z+bvv.z, acc1.w+bvv.w);
        *(float4*)(out + (size_t)nB*ND + col4*4) = r;
    }
}

// ---------------------------------------------------------------------------
// K7: edge attention weights (bf16 256B rows; den in qpe row tail).
// ---------------------------------------------------------------------------
__global__ __launch_bounds__(256) void k_edge(const int* __restrict__ ei,
    const ushort* __restrict__ qpe, const ushort* __restrict__ kpe,
    float* __restrict__ A, int E)
{
    int e = blockIdx.x*256 + threadIdx.x;
    if (e >= E) return;
    int s = ei[e], t = ei[E + e];
    const uint4* rq = (const uint4*)(qpe + (size_t)t*128);
    const uint4* rk = (const uint4*)(kpe + (size_t)s*128);
    float num[NH] = {0.f,0.f,0.f,0.f};
    #define ACC2(au,bu,idx0) { \
        float a0=__uint_as_float((au)<<16),        b0=__uint_as_float((bu)<<16); \
        float a1=__uint_as_float((au)&0xffff0000u),b1=__uint_as_float((bu)&0xffff0000u); \
        num[(idx0)/30]     = fmaf(a0,b0,num[(idx0)/30]); \
        num[((idx0)+1)/30] = fmaf(a1,b1,num[((idx0)+1)/30]); }
    #pragma unroll
    for (int j=0;j<15;j++){
        uint4 a = rq[j], b = rk[j];
        ACC2(a.x, b.x, j*8+0)
        ACC2(a.y, b.y, j*8+2)
        ACC2(a.z, b.z, j*8+4)
        ACC2(a.w, b.w, j*8+6)
    }
    #undef ACC2
    float4 dn = *(const float4*)((const float*)qpe + (size_t)t*64 + 60);
    float4 res = make_float4(num[0]/dn.x, num[1]/dn.y, num[2]/dn.z, num[3]/dn.w);
    *(float4*)(A + (size_t)e*4) = res;
}

// ---------------------------------------------------------------------------
extern "C" void kernel_launch(void* const* d_in, const int* in_sizes, int n_in,
                              void* d_out, int out_size, void* d_ws, size_t ws_size,
                              hipStream_t stream)
{
    const float* z    = (const float*)d_in[0];
    const int*   ei   = (const int*)d_in[1];
    const float* gum  = (const float*)d_in[2];
    const float* proj = (const float*)d_in[3];
    const float* Wq   = (const float*)d_in[4];
    const float* bq   = (const float*)d_in[5];
    const float* Wk   = (const float*)d_in[6];
    const float* bk   = (const float*)d_in[7];
    const float* Wv   = (const float*)d_in[8];
    const float* bv   = (const float*)d_in[9];
    const float* Wo   = (const float*)d_in[10];
    const float* Wob  = (const float*)d_in[11];
    int N = in_sizes[0] / NC;
    int E = in_sizes[1] / 2;

    float* ws = (float*)d_ws;
    size_t o = 0;
    #define ALIGN64 o = (o + 63) & ~(size_t)63;
    float* qp       = ws + o; o += (size_t)N*120;
    float* kp       = ws + o; o += (size_t)N*120;
    float* vbuf     = ws + o; float* z_out = vbuf;       o += (size_t)N*NHD;
    float* dd_k     = ws + o; float* kvs_part = dd_k;    o += (size_t)NH*N*NM;
    float* diag_k   = ws + o; o += (size_t)N*4;
    unsigned* mxk_u = (unsigned*)(ws + o); o += 4;
    int nkb = (N+127)/128;
    float* kp_part  = ws + o; o += (size_t)nkb*120;
    float* kp_sum   = ws + o; o += 120;
    float* kg_part  = ws + o; o += (size_t)NH*NK*S3*30;
    float* kvs      = ws + o; o += (size_t)NH*NK*1920;
    float* kg_sum   = ws + o; o += (size_t)NH*NK*30;
    ALIGN64
    ushort* qpe     = (ushort*)(ws + o); o += (size_t)N*64;
    ALIGN64
    ushort* kpe     = (ushort*)(ws + o); o += (size_t)N*64;
    ALIGN64
    ushort* Wt_h    = (ushort*)(ws + o); o += 48*4*64*8/2;   // 98304 ushorts
    ALIGN64
    ushort* Wt_l    = (ushort*)(ws + o); o += 48*4*64*8/2;
    ushort* v16     = (ushort*)vbuf;

    float* out = (float*)d_out;
    float* A   = out + (size_t)N*ND;

    k_wprep<<<dim3(48), dim3(256), 0, stream>>>(Wq, Wk, Wv, Wt_h, Wt_l);
    k_init<<<dim3(1), dim3(64), 0, stream>>>(mxk_u);
    k_qkv<<<dim3((N+15)/16), dim3(256), 0, stream>>>(z, Wt_h, Wt_l, bq, bk, bv, proj,
                                                     qp, qpe, dd_k, diag_k, v16, N);
    k_maxred<<<dim3(48,4), dim3(256), 0, stream>>>(dd_k, mxk_u, N);
    k_kp<<<dim3(nkb), dim3(256), 0, stream>>>(dd_k, diag_k, mxk_u, kp, kpe, kp_part, N);
    k_kpsred<<<dim3(1), dim3(128), 0, stream>>>(kp_part, kp_sum, nkb);
    k_kvs<<<dim3(S3, NK, NH), dim3(64), 0, stream>>>(kp, gum, v16, kvs_part, kg_part, N);
    k_kvsred<<<dim3(300), dim3(256), 0, stream>>>(kvs_part, kvs);
    k_kgred<<<dim3(5), dim3(256), 0, stream>>>(kg_part, kg_sum);
    k_z<<<dim3((N+255)/256, 4), dim3(256), 0, stream>>>(qp, kvs, kg_sum, kp_sum,
                                                        qpe, z_out, N);
    k_wo<<<dim3((N+31)/32), dim3(256), 0, stream>>>(z_out, Wo, Wob, out, N);
    k_edge<<<dim3((E+255)/256), dim3(256), 0, stream>>>(ei, qpe, kpe, A, E);
}

// Round 4
// 942.713 us; speedup vs baseline: 1.5851x; 1.2181x over previous
//
#include <hip/hip_runtime.h>
#include <math.h>

#define NH 4
#define ND 64
#define NC 128
#define NHD 256
#define NM 30
#define NK 10
#define EPSF 1e-6f
#define RATIO 0.18257418583505536f    // 1/sqrt(30)
#define QKSCALE 0.7071067811865476f   // inv_sqrt_tau(=2) * 64^{-1/4}(=0.353553)
#define NSEG 48                       // kvs2 n-segments (blocks = NSEG*NH)
#define NSEG2 128                     // kg_sum partial segments

typedef float f32x4 __attribute__((ext_vector_type(4)));
typedef short s16x8 __attribute__((ext_vector_type(8)));

__device__ __forceinline__ unsigned f2ord(float f){ unsigned b=__float_as_uint(f); return (b&0x80000000u)?~b:(b|0x80000000u); }
__device__ __forceinline__ float ord2f(unsigned u){ return __uint_as_float((u&0x80000000u)?(u&0x7fffffffu):~u); }
// round-to-nearest-even f32 -> bf16 (finite values)
__device__ __forceinline__ ushort f2bf(float f){ unsigned b=__float_as_uint(f); return (ushort)((b + 0x7fffu + ((b>>16)&1u))>>16); }
__device__ __forceinline__ float bf2f(ushort u){ return __uint_as_float(((unsigned)u)<<16); }
// split f32 -> bf16 hi + bf16 lo (hi round-half-up; lo truncated residual; hi+lo ~= p to 2^-17)
__device__ __forceinline__ void bfsplit(float p, unsigned& hi, unsigned& lo){
    unsigned pb = __float_as_uint(p);
    unsigned t  = pb + 0x8000u;
    unsigned hf = t & 0xffff0000u;
    hi = t >> 16;
    lo = __float_as_uint(p - __uint_as_float(hf)) >> 16;
}

__global__ void k_init(unsigned* mxk_u){ if (threadIdx.x < NH) mxk_u[threadIdx.x] = 0u; }

// ---------------------------------------------------------------------------
// K0: prep W (q|k|v concat, 768 cols) into MFMA B-fragment layout, bf16 hi/lo.
// ---------------------------------------------------------------------------
__global__ __launch_bounds__(256) void k_wprep(const float* __restrict__ Wq,
    const float* __restrict__ Wk, const float* __restrict__ Wv,
    ushort* __restrict__ Wt_h, ushort* __restrict__ Wt_l)
{
    int idx = blockIdx.x*256 + threadIdx.x;   // 48*4*64 = 12288
    if (idx >= 48*4*64) return;
    int lane = idx & 63, ks = (idx>>6)&3, tile = idx>>8;
    int c = tile*16 + (lane&15);
    int k0 = ks*32 + (lane>>4)*8;
    const float* W; int cc;
    if (c < 256)      { W = Wq; cc = c; }
    else if (c < 512) { W = Wk; cc = c-256; }
    else              { W = Wv; cc = c-512; }
    #pragma unroll
    for (int j=0;j<8;j++){
        float w = W[(size_t)(k0+j)*NHD + cc];
        ushort h = f2bf(w);
        Wt_h[(size_t)idx*8+j] = h;
        Wt_l[(size_t)idx*8+j] = f2bf(w - bf2f(h));
    }
}

// ---------------------------------------------------------------------------
// K-zfill: zero kpT pad rows (m=30,31), kpT row tails, vT16 row tails.
// ---------------------------------------------------------------------------
__global__ __launch_bounds__(256) void k_zfill(float* __restrict__ kpT,
    ushort* __restrict__ vT16, int N, int Npad)
{
    int tail = Npad - N;
    int w1 = 8*Npad, w2 = 128*tail, w3 = 256*tail;
    int idx = blockIdx.x*256 + threadIdx.x;
    if (idx < w1){
        int r = idx / Npad, c = idx % Npad;
        int hh = r>>1, m = 30 + (r&1);
        kpT[((size_t)(hh*32+m))*Npad + c] = 0.f;
    } else if (idx < w1+w2){
        int j = idx - w1; int r = j / tail, c = N + j % tail;
        kpT[(size_t)r*Npad + c] = 0.f;
    } else if (idx < w1+w2+w3){
        int j = idx - w1 - w2; int r = j / tail, c = N + j % tail;
        vT16[(size_t)r*Npad + c] = 0;
    }
}

// ---------------------------------------------------------------------------
// K1: QKV projection via 3-pass split-bf16 MFMA + q-features + dd_k/diag_k
// + transposed bf16 v panel (vT16[h*64+d][n]).  16 nodes/block.
// ---------------------------------------------------------------------------
__global__ __launch_bounds__(256) void k_qkv(
    const float* __restrict__ z,
    const ushort* __restrict__ Wt_h, const ushort* __restrict__ Wt_l,
    const float* __restrict__ bq, const float* __restrict__ bk,
    const float* __restrict__ bv, const float* __restrict__ proj,
    float* __restrict__ qp, ushort* __restrict__ qpe,
    float* __restrict__ dd_k, float* __restrict__ diag_k,
    ushort* __restrict__ vT16, int N, int Npad)
{
    const int NB = 16;
    __shared__ float xs[NB*8*65];      // 33.3 KB
    __shared__ float buf2[16*257];     // 16.4 KB: v staging (stride 257), then phase-2
    int tid = threadIdx.x;
    int n0 = blockIdx.x * NB;
    int w = tid >> 6, lane = tid & 63;
    int arow = lane & 15, kgrp = lane >> 4;

    // ---- A fragments (z rows), split bf16 hi/lo ----
    int nn = n0 + arow; if (nn > N-1) nn = N-1;
    const float* zrow = z + (size_t)nn*NC;
    s16x8 ah[4], al[4];
    #pragma unroll
    for (int ks=0;ks<4;ks++){
        f32x4 f0 = *(const f32x4*)(zrow + ks*32 + kgrp*8);
        f32x4 f1 = *(const f32x4*)(zrow + ks*32 + kgrp*8 + 4);
        #pragma unroll
        for (int j=0;j<4;j++){
            float v0 = f0[j]; ushort h0 = f2bf(v0);
            ah[ks][j]   = (short)h0; al[ks][j]   = (short)f2bf(v0 - bf2f(h0));
            float v1 = f1[j]; ushort h1 = f2bf(v1);
            ah[ks][4+j] = (short)h1; al[ks][4+j] = (short)f2bf(v1 - bf2f(h1));
        }
    }

    // ---- MFMA over 12 col-tiles per wave ----
    const uint4* WH = (const uint4*)Wt_h;
    const uint4* WL = (const uint4*)Wt_l;
    for (int nt=0; nt<12; nt++){
        int tile = w*12 + nt;
        f32x4 acc = {0.f,0.f,0.f,0.f};
        #pragma unroll
        for (int ks=0;ks<4;ks++){
            uint4 bhu = WH[(size_t)(tile*4+ks)*64 + lane];
            uint4 blu = WL[(size_t)(tile*4+ks)*64 + lane];
            s16x8 bh = __builtin_bit_cast(s16x8, bhu);
            s16x8 bl = __builtin_bit_cast(s16x8, blu);
            acc = __builtin_amdgcn_mfma_f32_16x16x32_bf16(ah[ks], bl, acc, 0,0,0);
            acc = __builtin_amdgcn_mfma_f32_16x16x32_bf16(al[ks], bh, acc, 0,0,0);
            acc = __builtin_amdgcn_mfma_f32_16x16x32_bf16(ah[ks], bh, acc, 0,0,0);
        }
        int tb = tile*16;
        int c  = tb + (lane&15);
        if (tb < 512) {
            int qk = c >> 8, ccc = c & 255;
            float bias = (qk==0) ? bq[ccc] : bk[ccc];
            int hh = ccc>>6, d = ccc&63;
            float* dst = &xs[(qk*4+hh)*65 + d];
            #pragma unroll
            for (int i=0;i<4;i++){
                int r = kgrp*4 + i;
                dst[r*520] = (acc[i] + bias) * QKSCALE;
            }
        } else {
            int cv = c - 512;
            float bias = bv[cv];
            #pragma unroll
            for (int i=0;i<4;i++){
                int r = kgrp*4 + i;
                buf2[r*257 + cv] = acc[i] + bias;
            }
        }
    }
    __syncthreads();

    // ---- vT16 store: thread owns d-row tid, 16 n's (32B contiguous) ----
    {
        int cv = tid;
        ushort tmp[16];
        #pragma unroll
        for (int r=0;r<16;r++) tmp[r] = f2bf(buf2[r*257+cv]);
        ushort* dst = &vT16[(size_t)cv*Npad + n0];
        if (n0 + 16 <= N) {
            uint4 p0, p1;
            p0.x = (unsigned)tmp[0] | ((unsigned)tmp[1]<<16);
            p0.y = (unsigned)tmp[2] | ((unsigned)tmp[3]<<16);
            p0.z = (unsigned)tmp[4] | ((unsigned)tmp[5]<<16);
            p0.w = (unsigned)tmp[6] | ((unsigned)tmp[7]<<16);
            p1.x = (unsigned)tmp[8] | ((unsigned)tmp[9]<<16);
            p1.y = (unsigned)tmp[10] | ((unsigned)tmp[11]<<16);
            p1.z = (unsigned)tmp[12] | ((unsigned)tmp[13]<<16);
            p1.w = (unsigned)tmp[14] | ((unsigned)tmp[15]<<16);
            *(uint4*)dst = p0;
            *(uint4*)(dst+8) = p1;
        } else {
            for (int r=0;r<16;r++) if (n0+r < N) dst[r] = tmp[r];
        }
    }
    __syncthreads();

    // ---- phase 2 overlays buf2 ----
    float* proj_s  = buf2;               // 30*65 = 1950
    float* ddq_s   = buf2 + 1952;        // 16*120 = 1920
    float* diagq_s = buf2 + 1952 + 1920; // 64   (total 3936 <= 4112)
    for (int i = tid; i < NM*ND; i += 256)
        proj_s[(i/ND)*65 + (i%ND)] = proj[i];
    __syncthreads();

    for (int i = tid; i < NB*240; i += 256) {
        int nb = i / 240, r = i % 240;
        int qk = r / 120, hm = r % 120;
        int hh = hm / 30, m = hm % 30;
        const float* xrow = &xs[(nb*8 + qk*4 + hh)*65];
        const float* prow = &proj_s[m*65];
        float s = 0.f;
        #pragma unroll
        for (int d=0; d<ND; d++) s = fmaf(xrow[d], prow[d], s);
        if (qk == 0) ddq_s[nb*120 + hm] = s;
        else { int n = n0+nb; if (n < N) dd_k[(size_t)hh*N*NM + (size_t)n*NM + m] = s; }
    }
    if (tid < NB*8) {
        int nb = tid/8, r = tid%8, qk = r/4, hh = r%4;
        const float* xrow = &xs[(nb*8 + qk*4 + hh)*65];
        float s = 0.f;
        #pragma unroll
        for (int d=0; d<ND; d++) s = fmaf(xrow[d], xrow[d], s);
        s *= 0.5f;
        if (qk == 0) diagq_s[nb*4+hh] = s;
        else { int n = n0+nb; if (n < N) diag_k[n*4+hh] = s; }
    }
    __syncthreads();

    for (int i = tid; i < NB*120; i += 256) {
        int nb = i/120, hm = i%120, hh = hm/30;
        int n = n0+nb;
        if (n >= N) continue;
        float mx = -3.0e38f;
        #pragma unroll
        for (int j=0;j<NM;j++) mx = fmaxf(mx, ddq_s[nb*120 + hh*30 + j]);
        float val = RATIO * (__expf(ddq_s[nb*120+hm] - diagq_s[nb*4+hh] - mx) + EPSF);
        qp[(size_t)n*120 + hm] = val;
        qpe[(size_t)n*128 + hm] = f2bf(val);
    }
}

// ---------------------------------------------------------------------------
// K1.5: global max of dd_k per head
// ---------------------------------------------------------------------------
__global__ __launch_bounds__(256) void k_maxred(const float* __restrict__ dd_k,
                                                unsigned* __restrict__ mxk_u, int N)
{
    int hh = blockIdx.y;
    size_t len = (size_t)N*NM;
    const float* p = dd_k + (size_t)hh*len;
    float mx = -3.0e38f;
    for (size_t i = (size_t)blockIdx.x*256 + threadIdx.x; i < len; i += (size_t)gridDim.x*256)
        mx = fmaxf(mx, p[i]);
    for (int o=32;o>0;o>>=1) mx = fmaxf(mx, __shfl_down(mx, o));
    __shared__ float wmax[4];
    if ((threadIdx.x & 63) == 0) wmax[threadIdx.x >> 6] = mx;
    __syncthreads();
    if (threadIdx.x == 0) {
        mx = fmaxf(fmaxf(wmax[0],wmax[1]), fmaxf(wmax[2],wmax[3]));
        atomicMax(&mxk_u[hh], f2ord(mx));
    }
}

// ---------------------------------------------------------------------------
// K2: kp features -> kpe (bf16 edge rows), kpT (f32 transposed panel), partial sums.
// ---------------------------------------------------------------------------
__global__ __launch_bounds__(256) void k_kp(const float* __restrict__ dd_k,
    const float* __restrict__ diag_k, const unsigned* __restrict__ mxk_u,
    ushort* __restrict__ kpe, float* __restrict__ kpT,
    float* __restrict__ kp_part, int N, int Npad)
{
    __shared__ float psum[120];
    int tid = threadIdx.x;
    if (tid < 120) psum[tid] = 0.f;
    float mxk[NH];
    #pragma unroll
    for (int hh=0;hh<NH;hh++) mxk[hh] = ord2f(mxk_u[hh]);
    __syncthreads();
    int n0 = blockIdx.x * 128;
    for (int r = 0; r < 60; r++) {
        int idx = r*256 + tid;
        int nl = idx / 120, hm = idx % 120;
        int n = n0 + nl;
        if (n >= N) break;
        int hh = hm/30, m = hm%30;
        float val = RATIO * (__expf(dd_k[(size_t)hh*N*NM + (size_t)n*NM + m]
                                    - diag_k[n*4+hh] - mxk[hh]) + EPSF);
        kpe[(size_t)n*128 + hm] = f2bf(val);
        kpT[((size_t)(hh*32+m))*Npad + n] = val;
        atomicAdd(&psum[hm], val);
    }
    __syncthreads();
    if (tid < 120) kp_part[blockIdx.x*120 + tid] = psum[tid];
}

__global__ void k_kpsred(const float* __restrict__ kp_part, float* __restrict__ kp_sum, int nblk){
    int t = threadIdx.x;
    if (t < 120) {
        float s = 0.f;
        for (int b=0;b<nblk;b++) s += kp_part[b*120+t];
        kp_sum[t] = s;
    }
}

// ---------------------------------------------------------------------------
// K-eg: egT[hk][n] = exp(gum[n][hk]), zero tail.
// ---------------------------------------------------------------------------
__global__ __launch_bounds__(256) void k_eg(const float* __restrict__ gum,
    float* __restrict__ egT, int N, int Npad)
{
    int n0 = blockIdx.x*64;
    for (int i = threadIdx.x; i < 64*40; i += 256){
        int nl = i / 40, hk = i % 40;
        int n = n0 + nl;
        if (n >= Npad) continue;
        float v = (n < N) ? __expf(gum[(size_t)n*40 + hk]) : 0.f;
        egT[(size_t)hk*Npad + n] = v;
    }
}

// ---------------------------------------------------------------------------
// K3: kvs via MFMA.  Block = (seg, h), 4 waves; wave owns 80 (k,m)-rows.
// A = kg = kpT*egT (f32 product, split hi/lo bf16), B = vT16.
// Out: part[(h*NSEG+seg)][320][64] f32.
// ---------------------------------------------------------------------------
__global__ __launch_bounds__(256,1) void k_kvs2(const float* __restrict__ kpT,
    const float* __restrict__ egT, const ushort* __restrict__ vT16,
    float* __restrict__ part, int Npad)
{
    int seg = blockIdx.x, hh = blockIdx.y;
    int w = threadIdx.x >> 6, lane = threadIdx.x & 63;
    int l15 = lane & 15, lg = lane >> 4;
    int steps_total = Npad/32;
    int per = (steps_total + NSEG-1)/NSEG;
    int s0 = seg*per, s1 = min(steps_total, s0+per);

    const ushort* vbase = vT16 + (size_t)hh*64*Npad;
    const float* kpbase = kpT + (size_t)hh*32*Npad;
    const float* egbase = egT + (size_t)hh*10*Npad;

    f32x4 acc[5][4];
    #pragma unroll
    for (int mt=0;mt<5;mt++)
        #pragma unroll
        for (int nt=0;nt<4;nt++) acc[mt][nt] = (f32x4){0.f,0.f,0.f,0.f};

    for (int st = s0; st < s1; ++st){
        int n0 = st*32 + lg*8;
        s16x8 bf[4];
        #pragma unroll
        for (int nt=0;nt<4;nt++){
            uint4 u = *(const uint4*)(vbase + (size_t)(nt*16 + l15)*Npad + n0);
            bf[nt] = __builtin_bit_cast(s16x8, u);
        }
        #pragma unroll
        for (int mt=0;mt<5;mt++){
            int r = w*80 + mt*16 + l15;
            int m = r & 31, kk = r >> 5;
            const float* kprow = kpbase + (size_t)m*Npad;
            const float* egrow = egbase + (size_t)kk*Npad;
            f32x4 kp0 = *(const f32x4*)(kprow + n0);
            f32x4 kp1 = *(const f32x4*)(kprow + n0 + 4);
            f32x4 eg0 = *(const f32x4*)(egrow + n0);
            f32x4 eg1 = *(const f32x4*)(egrow + n0 + 4);
            f32x4 pr0 = kp0*eg0, pr1 = kp1*eg1;
            unsigned hi[8], lo[8];
            #pragma unroll
            for (int j=0;j<4;j++){
                bfsplit(pr0[j], hi[j], lo[j]);
                bfsplit(pr1[j], hi[4+j], lo[4+j]);
            }
            uint4 ahu, alu;
            ahu.x = hi[0]|(hi[1]<<16); ahu.y = hi[2]|(hi[3]<<16);
            ahu.z = hi[4]|(hi[5]<<16); ahu.w = hi[6]|(hi[7]<<16);
            alu.x = lo[0]|(lo[1]<<16); alu.y = lo[2]|(lo[3]<<16);
            alu.z = lo[4]|(lo[5]<<16); alu.w = lo[6]|(lo[7]<<16);
            s16x8 ah = __builtin_bit_cast(s16x8, ahu);
            s16x8 al = __builtin_bit_cast(s16x8, alu);
            #pragma unroll
            for (int nt=0;nt<4;nt++){
                acc[mt][nt] = __builtin_amdgcn_mfma_f32_16x16x32_bf16(al, bf[nt], acc[mt][nt], 0,0,0);
                acc[mt][nt] = __builtin_amdgcn_mfma_f32_16x16x32_bf16(ah, bf[nt], acc[mt][nt], 0,0,0);
            }
        }
    }
    float* dst = part + ((size_t)hh*NSEG + seg)*20480;
    #pragma unroll
    for (int mt=0;mt<5;mt++)
        #pragma unroll
        for (int nt=0;nt<4;nt++)
            #pragma unroll
            for (int i=0;i<4;i++){
                int rr = w*80 + mt*16 + lg*4 + i;
                dst[rr*64 + nt*16 + l15] = acc[mt][nt][i];
            }
}

__global__ void k_kvsred2(const float* __restrict__ part, float* __restrict__ kvs){
    int o = blockIdx.x*256 + threadIdx.x;   // 76800 = 4h*10k*30m*64d
    if (o >= 76800) return;
    int hh = o / 19200, r = o % 19200;
    int km = r >> 6, d = r & 63;
    int kk = km / 30, m = km % 30;
    size_t base = (size_t)hh*NSEG*20480 + (size_t)(kk*32+m)*64 + d;
    float s = 0.f;
    for (int sg=0; sg<NSEG; sg++) s += part[base + (size_t)sg*20480];
    kvs[o] = s;
}

// ---------------------------------------------------------------------------
// kg_sum = sum_n kpT*egT (f32 exact), partials over NSEG2 segments.
// ---------------------------------------------------------------------------
__global__ __launch_bounds__(320) void k_kgp(const float* __restrict__ kpT,
    const float* __restrict__ egT, float* __restrict__ kg_part, int Npad)
{
    int s2 = blockIdx.x, hh = blockIdx.y;
    int t = threadIdx.x;                 // 320: kk = t/32, m = t&31
    int kk = t >> 5, m = t & 31;
    int len = Npad / NSEG2;              // multiple of 4 (Npad mult of 512)
    int n0 = s2*len;
    float acc = 0.f;
    if (kk < NK && m < NM){
        const f32x4* kr = (const f32x4*)(kpT + ((size_t)(hh*32+m))*Npad + n0);
        const f32x4* er = (const f32x4*)(egT + ((size_t)(hh*10+kk))*Npad + n0);
        for (int i=0;i<len/4;i++){
            f32x4 a = kr[i], b = er[i];
            acc = fmaf(a.x, b.x, acc); acc = fmaf(a.y, b.y, acc);
            acc = fmaf(a.z, b.z, acc); acc = fmaf(a.w, b.w, acc);
        }
    }
    kg_part[((size_t)hh*NSEG2 + s2)*320 + t] = acc;
}

__global__ void k_kgred2(const float* __restrict__ kg_part, float* __restrict__ kg_sum){
    int o = blockIdx.x*64 + threadIdx.x;   // 1200
    if (o >= 1200) return;
    int hh = o / 300, r = o % 300;
    int kk = r / 30, m = r % 30;
    float s = 0.f;
    for (int i=0;i<NSEG2;i++) s += kg_part[((size_t)hh*NSEG2 + i)*320 + kk*32 + m];
    kg_sum[o] = s;
}

// ---------------------------------------------------------------------------
// K5: per-node z_out; den written into qpe row tail.
// ---------------------------------------------------------------------------
__global__ __launch_bounds__(256) void k_z(const float* __restrict__ qp,
    const float* __restrict__ kvs, const float* __restrict__ kg_sum,
    const float* __restrict__ kp_sum, ushort* __restrict__ qpe,
    float* __restrict__ z_out, int N)
{
    __shared__ float kvs_s[5*30*64];
    __shared__ float kg_s[NK*30];
    __shared__ float kps_s[30];
    int tid = threadIdx.x;
    int hh = blockIdx.y;
    int n = blockIdx.x*256 + tid;
    bool valid = (n < N);

    for (int i=tid;i<300;i+=256) kg_s[i] = kg_sum[hh*300+i];
    if (tid<30) kps_s[tid] = kp_sum[hh*30+tid];
    for (int i=tid;i<9600;i+=256) kvs_s[i] = kvs[(size_t)hh*19200 + i];
    __syncthreads();

    float qv[NM]; float scale[NK];
    if (valid) {
        const float2* q2 = (const float2*)(qp + (size_t)n*120 + hh*30);
        #pragma unroll
        for (int j=0;j<15;j++){ float2 t = q2[j]; qv[2*j]=t.x; qv[2*j+1]=t.y; }
        float dn = 0.f;
        #pragma unroll
        for (int m=0;m<NM;m++) dn = fmaf(qv[m], kps_s[m], dn);
        ((float*)qpe)[(size_t)n*64 + 60 + hh] = dn;
        #pragma unroll
        for (int k=0;k<NK;k++){
            float s=0.f;
            #pragma unroll
            for (int m=0;m<NM;m++) s = fmaf(qv[m], kg_s[k*30+m], s);
            scale[k] = (1.0f/NK) / s;
        }
    }
    float4 zacc[16];
    #pragma unroll
    for (int i=0;i<16;i++) zacc[i] = make_float4(0.f,0.f,0.f,0.f);

    if (valid) {
        for (int k=0;k<5;k++)
            for (int m=0;m<NM;m++){
                float w = qv[m]*scale[k];
                const float4* kr = (const float4*)&kvs_s[(k*30+m)*64];
                #pragma unroll
                for (int d4=0; d4<16; d4++){
                    float4 kv = kr[d4];
                    zacc[d4].x = fmaf(w, kv.x, zacc[d4].x);
                    zacc[d4].y = fmaf(w, kv.y, zacc[d4].y);
                    zacc[d4].z = fmaf(w, kv.z, zacc[d4].z);
                    zacc[d4].w = fmaf(w, kv.w, zacc[d4].w);
                }
            }
    }
    __syncthreads();
    for (int i=tid;i<9600;i+=256) kvs_s[i] = kvs[(size_t)hh*19200 + 9600 + i];
    __syncthreads();
    if (valid) {
        for (int k=0;k<5;k++)
            for (int m=0;m<NM;m++){
                float w = qv[m]*scale[5+k];
                const float4* kr = (const float4*)&kvs_s[(k*30+m)*64];
                #pragma unroll
                for (int d4=0; d4<16; d4++){
                    float4 kv = kr[d4];
                    zacc[d4].x = fmaf(w, kv.x, zacc[d4].x);
                    zacc[d4].y = fmaf(w, kv.y, zacc[d4].y);
                    zacc[d4].z = fmaf(w, kv.z, zacc[d4].z);
                    zacc[d4].w = fmaf(w, kv.w, zacc[d4].w);
                }
            }
        float4* zo = (float4*)(z_out + (size_t)n*NHD + hh*64);
        #pragma unroll
        for (int d4=0;d4<16;d4++) zo[d4] = zacc[d4];
    }
}

// ---------------------------------------------------------------------------
// K6: out = z_out @ Wo + b.
// ---------------------------------------------------------------------------
__global__ __launch_bounds__(256) void k_wo(const float* __restrict__ z_out,
    const float* __restrict__ Wo, const float* __restrict__ Wob,
    float* __restrict__ out, int N)
{
    __shared__ float wo_s[128*64];
    __shared__ float z_s[32*128];
    int tid = threadIdx.x;
    int n0 = blockIdx.x*32;
    int col4 = tid & 15, nl = tid >> 4;
    float4 acc0 = make_float4(0.f,0.f,0.f,0.f), acc1 = acc0;
    for (int jh=0; jh<2; jh++){
        __syncthreads();
        for (int i=tid;i<128*64;i+=256) wo_s[i] = Wo[jh*128*64 + i];
        for (int i=tid;i<32*128;i+=256){
            int nn = n0 + i/128;
            z_s[i] = (nn<N)? z_out[(size_t)nn*NHD + jh*128 + (i%128)] : 0.f;
        }
        __syncthreads();
        for (int j=0;j<128;j++){
            float4 w4 = *(const float4*)&wo_s[j*64 + col4*4];
            float zv0 = z_s[nl*128 + j];
            float zv1 = z_s[(nl+16)*128 + j];
            acc0.x = fmaf(zv0, w4.x, acc0.x); acc0.y = fmaf(zv0, w4.y, acc0.y);
            acc0.z = fmaf(zv0, w4.z, acc0.z); acc0.w = fmaf(zv0, w4.w, acc0.w);
            acc1.x = fmaf(zv1, w4.x, acc1.x); acc1.y = fmaf(zv1, w4.y, acc1.y);
            acc1.z = fmaf(zv1, w4.z, acc1.z); acc1.w = fmaf(zv1, w4.w, acc1.w);
        }
    }
    float4 bvv = *(const float4*)&Wob[col4*4];
    int nA = n0+nl, nB = n0+nl+16;
    if (nA < N) {
        float4 r = make_float4(acc0.x+bvv.x, acc0.y+bvv.y, acc0.z+bvv.z, acc0.w+bvv.w);
        *(float4*)(out + (size_t)nA*ND + col4*4) = r;
    }
    if (nB < N) {
        float4 r = make_float4(acc1.x+bvv.x, acc1.y+bvv.y, acc1.z+bvv.z, acc1.w+bvv.w);
        *(float4*)(out + (size_t)nB*ND + col4*4) = r;
    }
}

// ---------------------------------------------------------------------------
// K7: edge attention weights (bf16 256B rows; den in qpe row tail).
// ---------------------------------------------------------------------------
__global__ __launch_bounds__(256) void k_edge(const int* __restrict__ ei,
    const ushort* __restrict__ qpe, const ushort* __restrict__ kpe,
    float* __restrict__ A, int E)
{
    int e = blockIdx.x*256 + threadIdx.x;
    if (e >= E) return;
    int s = ei[e], t = ei[E + e];
    const uint4* rq = (const uint4*)(qpe + (size_t)t*128);
    const uint4* rk = (const uint4*)(kpe + (size_t)s*128);
    float num[NH] = {0.f,0.f,0.f,0.f};
    #define ACC2(au,bu,idx0) { \
        float a0=__uint_as_float((au)<<16),        b0=__uint_as_float((bu)<<16); \
        float a1=__uint_as_float((au)&0xffff0000u),b1=__uint_as_float((bu)&0xffff0000u); \
        num[(idx0)/30]     = fmaf(a0,b0,num[(idx0)/30]); \
        num[((idx0)+1)/30] = fmaf(a1,b1,num[((idx0)+1)/30]); }
    #pragma unroll
    for (int j=0;j<15;j++){
        uint4 a = rq[j], b = rk[j];
        ACC2(a.x, b.x, j*8+0)
        ACC2(a.y, b.y, j*8+2)
        ACC2(a.z, b.z, j*8+4)
        ACC2(a.w, b.w, j*8+6)
    }
    #undef ACC2
    float4 dn = *(const float4*)((const float*)qpe + (size_t)t*64 + 60);
    float4 res = make_float4(num[0]/dn.x, num[1]/dn.y, num[2]/dn.z, num[3]/dn.w);
    *(float4*)(A + (size_t)e*4) = res;
}

// ---------------------------------------------------------------------------
extern "C" void kernel_launch(void* const* d_in, const int* in_sizes, int n_in,
                              void* d_out, int out_size, void* d_ws, size_t ws_size,
                              hipStream_t stream)
{
    const float* z    = (const float*)d_in[0];
    const int*   ei   = (const int*)d_in[1];
    const float* gum  = (const float*)d_in[2];
    const float* proj = (const float*)d_in[3];
    const float* Wq   = (const float*)d_in[4];
    const float* bq   = (const float*)d_in[5];
    const float* Wk   = (const float*)d_in[6];
    const float* bk   = (const float*)d_in[7];
    const float* Wv   = (const float*)d_in[8];
    const float* bv   = (const float*)d_in[9];
    const float* Wo   = (const float*)d_in[10];
    const float* Wob  = (const float*)d_in[11];
    int N = in_sizes[0] / NC;
    int E = in_sizes[1] / 2;
    int Npad = (N + 511) & ~511;

    float* ws = (float*)d_ws;
    size_t o = 0;
    #define ALIGN64 o = (o + 63) & ~(size_t)63;
    float* qp       = ws + o; o += (size_t)N*120;
    ALIGN64
    float* vbuf     = ws + o; float* z_out = vbuf;       o += (size_t)N*NHD;
    ALIGN64
    float* dd_k     = ws + o; o += (size_t)NH*N*NM;      // later: egT + kvs_part2
    float* egT      = dd_k;                              // 40*Npad
    float* kvs_part = dd_k + (size_t)40*Npad;            // NSEG*4*20480 (fits in dd_k: 48*4*20480+40*Npad <= 4*N*30 for N=50000)
    ALIGN64
    float* diag_k   = ws + o; o += (size_t)N*4;
    unsigned* mxk_u = (unsigned*)(ws + o); o += 4;
    ALIGN64
    int nkb = (N+127)/128;
    float* kp_part  = ws + o; o += (size_t)nkb*120;
    float* kp_sum   = ws + o; o += 120;
    ALIGN64
    float* kg_part  = ws + o; o += (size_t)NH*NSEG2*320;
    float* kvs      = ws + o; o += 76800;
    float* kg_sum   = ws + o; o += 1200;
    ALIGN64
    ushort* qpe     = (ushort*)(ws + o); o += (size_t)N*64;
    ALIGN64
    ushort* kpe     = (ushort*)(ws + o); o += (size_t)N*64;
    ALIGN64
    ushort* Wt_h    = (ushort*)(ws + o); o += 48*4*64*8/2;
    ALIGN64
    ushort* Wt_l    = (ushort*)(ws + o); o += 48*4*64*8/2;
    ALIGN64
    float* kpT      = ws + o; o += (size_t)128*Npad;
    ushort* vT16    = (ushort*)vbuf;                     // 256*Npad ushorts (dead before z_out)

    float* out = (float*)d_out;
    float* A   = out + (size_t)N*ND;

    k_wprep<<<dim3(48), dim3(256), 0, stream>>>(Wq, Wk, Wv, Wt_h, Wt_l);
    k_init<<<dim3(1), dim3(64), 0, stream>>>(mxk_u);
    {
        int tail = Npad - N;
        int zwork = 8*Npad + (128+256)*tail;
        k_zfill<<<dim3((zwork+255)/256), dim3(256), 0, stream>>>(kpT, vT16, N, Npad);
    }
    k_qkv<<<dim3((N+15)/16), dim3(256), 0, stream>>>(z, Wt_h, Wt_l, bq, bk, bv, proj,
                                                     qp, qpe, dd_k, diag_k, vT16, N, Npad);
    k_maxred<<<dim3(48,4), dim3(256), 0, stream>>>(dd_k, mxk_u, N);
    k_kp<<<dim3(nkb), dim3(256), 0, stream>>>(dd_k, diag_k, mxk_u, kpe, kpT, kp_part, N, Npad);
    k_kpsred<<<dim3(1), dim3(128), 0, stream>>>(kp_part, kp_sum, nkb);
    k_eg<<<dim3(Npad/64), dim3(256), 0, stream>>>(gum, egT, N, Npad);
    k_kvs2<<<dim3(NSEG, NH), dim3(256), 0, stream>>>(kpT, egT, vT16, kvs_part, Npad);
    k_kgp<<<dim3(NSEG2, NH), dim3(320), 0, stream>>>(kpT, egT, kg_part, Npad);
    k_kvsred2<<<dim3(300), dim3(256), 0, stream>>>(kvs_part, kvs);
    k_kgred2<<<dim3(19), dim3(64), 0, stream>>>(kg_part, kg_sum);
    k_z<<<dim3((N+255)/256, 4), dim3(256), 0, stream>>>(qp, kvs, kg_sum, kp_sum,
                                                        qpe, z_out, N);
    k_wo<<<dim3((N+31)/32), dim3(256), 0, stream>>>(z_out, Wo, Wob, out, N);
    k_edge<<<dim3((E+255)/256), dim3(256), 0, stream>>>(ei, qpe, kpe, A, E);
}

// Round 5
// 707.694 us; speedup vs baseline: 2.1116x; 1.3321x over previous
//
#include <hip/hip_runtime.h>
#include <math.h>

#define NH 4
#define ND 64
#define NC 128
#define NHD 256
#define NM 30
#define NK 10
#define EPSF 1e-6f
#define RATIO 0.18257418583505536f    // 1/sqrt(30)
#define QKSCALE 0.7071067811865476f   // inv_sqrt_tau(=2) * 64^{-1/4}(=0.353553)
#define NSEG 48                       // kvs2 n-segments (blocks = NSEG*NH)
#define NSEG2 128                     // kg_sum partial segments

typedef float f32x4 __attribute__((ext_vector_type(4)));
typedef short s16x8 __attribute__((ext_vector_type(8)));

__device__ __forceinline__ unsigned f2ord(float f){ unsigned b=__float_as_uint(f); return (b&0x80000000u)?~b:(b|0x80000000u); }
__device__ __forceinline__ float ord2f(unsigned u){ return __uint_as_float((u&0x80000000u)?(u&0x7fffffffu):~u); }
// round-to-nearest-even f32 -> bf16 (finite values)
__device__ __forceinline__ ushort f2bf(float f){ unsigned b=__float_as_uint(f); return (ushort)((b + 0x7fffu + ((b>>16)&1u))>>16); }
__device__ __forceinline__ float bf2f(ushort u){ return __uint_as_float(((unsigned)u)<<16); }
// split f32 -> bf16 hi + bf16 lo (hi+lo ~= p to 2^-17 rel)
__device__ __forceinline__ void bfsplit(float p, unsigned& hi, unsigned& lo){
    unsigned pb = __float_as_uint(p);
    unsigned t  = pb + 0x8000u;
    unsigned hf = t & 0xffff0000u;
    hi = t >> 16;
    lo = __float_as_uint(p - __uint_as_float(hf)) >> 16;
}

__global__ void k_init(unsigned* mxk_u){ if (threadIdx.x < NH) mxk_u[threadIdx.x] = 0u; }

// ---------------------------------------------------------------------------
// K0: prep W (q|k|v concat, 768 cols) into MFMA B-fragment layout, bf16 hi/lo.
// ---------------------------------------------------------------------------
__global__ __launch_bounds__(256) void k_wprep(const float* __restrict__ Wq,
    const float* __restrict__ Wk, const float* __restrict__ Wv,
    ushort* __restrict__ Wt_h, ushort* __restrict__ Wt_l)
{
    int idx = blockIdx.x*256 + threadIdx.x;   // 48*4*64 = 12288
    if (idx >= 48*4*64) return;
    int lane = idx & 63, ks = (idx>>6)&3, tile = idx>>8;
    int c = tile*16 + (lane&15);
    int k0 = ks*32 + (lane>>4)*8;
    const float* W; int cc;
    if (c < 256)      { W = Wq; cc = c; }
    else if (c < 512) { W = Wk; cc = c-256; }
    else              { W = Wv; cc = c-512; }
    #pragma unroll
    for (int j=0;j<8;j++){
        float w = W[(size_t)(k0+j)*NHD + cc];
        ushort h = f2bf(w);
        Wt_h[(size_t)idx*8+j] = h;
        Wt_l[(size_t)idx*8+j] = f2bf(w - bf2f(h));
    }
}

// ---------------------------------------------------------------------------
// K-zfill: zero kpT pad rows (m=30,31), kpT row tails, vT16 row tails.
// ---------------------------------------------------------------------------
__global__ __launch_bounds__(256) void k_zfill(float* __restrict__ kpT,
    ushort* __restrict__ vT16, int N, int Npad)
{
    int tail = Npad - N;
    int w1 = 8*Npad, w2 = 128*tail, w3 = 256*tail;
    int idx = blockIdx.x*256 + threadIdx.x;
    if (idx < w1){
        int r = idx / Npad, c = idx % Npad;
        int hh = r>>1, m = 30 + (r&1);
        kpT[((size_t)(hh*32+m))*Npad + c] = 0.f;
    } else if (idx < w1+w2){
        int j = idx - w1; int r = j / tail, c = N + j % tail;
        kpT[(size_t)r*Npad + c] = 0.f;
    } else if (idx < w1+w2+w3){
        int j = idx - w1 - w2; int r = j / tail, c = N + j % tail;
        vT16[(size_t)r*Npad + c] = 0;
    }
}

// ---------------------------------------------------------------------------
// K1: QKV projection via 3-pass split-bf16 MFMA + q-features + dd_k/diag_k
// + transposed bf16 v panel (vT16[h*64+d][n]).  16 nodes/block.
// ---------------------------------------------------------------------------
__global__ __launch_bounds__(256) void k_qkv(
    const float* __restrict__ z,
    const ushort* __restrict__ Wt_h, const ushort* __restrict__ Wt_l,
    const float* __restrict__ bq, const float* __restrict__ bk,
    const float* __restrict__ bv, const float* __restrict__ proj,
    float* __restrict__ qp, ushort* __restrict__ qpe,
    float* __restrict__ dd_k, float* __restrict__ diag_k,
    ushort* __restrict__ vT16, int N, int Npad)
{
    const int NB = 16;
    __shared__ float xs[NB*8*65];      // 33.3 KB
    __shared__ float buf2[16*257];     // 16.4 KB: v staging (stride 257), then phase-2
    int tid = threadIdx.x;
    int n0 = blockIdx.x * NB;
    int w = tid >> 6, lane = tid & 63;
    int arow = lane & 15, kgrp = lane >> 4;

    // ---- A fragments (z rows), split bf16 hi/lo ----
    int nn = n0 + arow; if (nn > N-1) nn = N-1;
    const float* zrow = z + (size_t)nn*NC;
    s16x8 ah[4], al[4];
    #pragma unroll
    for (int ks=0;ks<4;ks++){
        f32x4 f0 = *(const f32x4*)(zrow + ks*32 + kgrp*8);
        f32x4 f1 = *(const f32x4*)(zrow + ks*32 + kgrp*8 + 4);
        #pragma unroll
        for (int j=0;j<4;j++){
            float v0 = f0[j]; ushort h0 = f2bf(v0);
            ah[ks][j]   = (short)h0; al[ks][j]   = (short)f2bf(v0 - bf2f(h0));
            float v1 = f1[j]; ushort h1 = f2bf(v1);
            ah[ks][4+j] = (short)h1; al[ks][4+j] = (short)f2bf(v1 - bf2f(h1));
        }
    }

    // ---- MFMA over 12 col-tiles per wave ----
    const uint4* WH = (const uint4*)Wt_h;
    const uint4* WL = (const uint4*)Wt_l;
    for (int nt=0; nt<12; nt++){
        int tile = w*12 + nt;
        f32x4 acc = {0.f,0.f,0.f,0.f};
        #pragma unroll
        for (int ks=0;ks<4;ks++){
            uint4 bhu = WH[(size_t)(tile*4+ks)*64 + lane];
            uint4 blu = WL[(size_t)(tile*4+ks)*64 + lane];
            s16x8 bh = __builtin_bit_cast(s16x8, bhu);
            s16x8 bl = __builtin_bit_cast(s16x8, blu);
            acc = __builtin_amdgcn_mfma_f32_16x16x32_bf16(ah[ks], bl, acc, 0,0,0);
            acc = __builtin_amdgcn_mfma_f32_16x16x32_bf16(al[ks], bh, acc, 0,0,0);
            acc = __builtin_amdgcn_mfma_f32_16x16x32_bf16(ah[ks], bh, acc, 0,0,0);
        }
        int tb = tile*16;
        int c  = tb + (lane&15);
        if (tb < 512) {
            int qk = c >> 8, ccc = c & 255;
            float bias = (qk==0) ? bq[ccc] : bk[ccc];
            int hh = ccc>>6, d = ccc&63;
            float* dst = &xs[(qk*4+hh)*65 + d];
            #pragma unroll
            for (int i=0;i<4;i++){
                int r = kgrp*4 + i;
                dst[r*520] = (acc[i] + bias) * QKSCALE;
            }
        } else {
            int cv = c - 512;
            float bias = bv[cv];
            #pragma unroll
            for (int i=0;i<4;i++){
                int r = kgrp*4 + i;
                buf2[r*257 + cv] = acc[i] + bias;
            }
        }
    }
    __syncthreads();

    // ---- vT16 store: thread owns d-row tid, 16 n's (32B contiguous) ----
    {
        int cv = tid;
        ushort tmp[16];
        #pragma unroll
        for (int r=0;r<16;r++) tmp[r] = f2bf(buf2[r*257+cv]);
        ushort* dst = &vT16[(size_t)cv*Npad + n0];
        if (n0 + 16 <= N) {
            uint4 p0, p1;
            p0.x = (unsigned)tmp[0] | ((unsigned)tmp[1]<<16);
            p0.y = (unsigned)tmp[2] | ((unsigned)tmp[3]<<16);
            p0.z = (unsigned)tmp[4] | ((unsigned)tmp[5]<<16);
            p0.w = (unsigned)tmp[6] | ((unsigned)tmp[7]<<16);
            p1.x = (unsigned)tmp[8] | ((unsigned)tmp[9]<<16);
            p1.y = (unsigned)tmp[10] | ((unsigned)tmp[11]<<16);
            p1.z = (unsigned)tmp[12] | ((unsigned)tmp[13]<<16);
            p1.w = (unsigned)tmp[14] | ((unsigned)tmp[15]<<16);
            *(uint4*)dst = p0;
            *(uint4*)(dst+8) = p1;
        } else {
            for (int r=0;r<16;r++) if (n0+r < N) dst[r] = tmp[r];
        }
    }
    __syncthreads();

    // ---- phase 2 overlays buf2 ----
    float* proj_s  = buf2;               // 30*65 = 1950
    float* ddq_s   = buf2 + 1952;        // 16*120 = 1920
    float* diagq_s = buf2 + 1952 + 1920; // 64   (total 3936 <= 4112)
    for (int i = tid; i < NM*ND; i += 256)
        proj_s[(i/ND)*65 + (i%ND)] = proj[i];
    __syncthreads();

    for (int i = tid; i < NB*240; i += 256) {
        int nb = i / 240, r = i % 240;
        int qk = r / 120, hm = r % 120;
        int hh = hm / 30, m = hm % 30;
        const float* xrow = &xs[(nb*8 + qk*4 + hh)*65];
        const float* prow = &proj_s[m*65];
        float s = 0.f;
        #pragma unroll
        for (int d=0; d<ND; d++) s = fmaf(xrow[d], prow[d], s);
        if (qk == 0) ddq_s[nb*120 + hm] = s;
        else { int n = n0+nb; if (n < N) dd_k[(size_t)hh*N*NM + (size_t)n*NM + m] = s; }
    }
    if (tid < NB*8) {
        int nb = tid/8, r = tid%8, qk = r/4, hh = r%4;
        const float* xrow = &xs[(nb*8 + qk*4 + hh)*65];
        float s = 0.f;
        #pragma unroll
        for (int d=0; d<ND; d++) s = fmaf(xrow[d], xrow[d], s);
        s *= 0.5f;
        if (qk == 0) diagq_s[nb*4+hh] = s;
        else { int n = n0+nb; if (n < N) diag_k[n*4+hh] = s; }
    }
    __syncthreads();

    for (int i = tid; i < NB*120; i += 256) {
        int nb = i/120, hm = i%120, hh = hm/30;
        int n = n0+nb;
        if (n >= N) continue;
        float mx = -3.0e38f;
        #pragma unroll
        for (int j=0;j<NM;j++) mx = fmaxf(mx, ddq_s[nb*120 + hh*30 + j]);
        float val = RATIO * (__expf(ddq_s[nb*120+hm] - diagq_s[nb*4+hh] - mx) + EPSF);
        qp[(size_t)n*120 + hm] = val;
        qpe[(size_t)n*128 + hm] = f2bf(val);
    }
}

// ---------------------------------------------------------------------------
// K1.5: global max of dd_k per head
// ---------------------------------------------------------------------------
__global__ __launch_bounds__(256) void k_maxred(const float* __restrict__ dd_k,
                                                unsigned* __restrict__ mxk_u, int N)
{
    int hh = blockIdx.y;
    size_t len = (size_t)N*NM;
    const float* p = dd_k + (size_t)hh*len;
    float mx = -3.0e38f;
    for (size_t i = (size_t)blockIdx.x*256 + threadIdx.x; i < len; i += (size_t)gridDim.x*256)
        mx = fmaxf(mx, p[i]);
    for (int o=32;o>0;o>>=1) mx = fmaxf(mx, __shfl_down(mx, o));
    __shared__ float wmax[4];
    if ((threadIdx.x & 63) == 0) wmax[threadIdx.x >> 6] = mx;
    __syncthreads();
    if (threadIdx.x == 0) {
        mx = fmaxf(fmaxf(wmax[0],wmax[1]), fmaxf(wmax[2],wmax[3]));
        atomicMax(&mxk_u[hh], f2ord(mx));
    }
}

// ---------------------------------------------------------------------------
// K2: kp features -> kpe (bf16 edge rows), kpT (f32 transposed panel), partial sums.
// ---------------------------------------------------------------------------
__global__ __launch_bounds__(256) void k_kp(const float* __restrict__ dd_k,
    const float* __restrict__ diag_k, const unsigned* __restrict__ mxk_u,
    ushort* __restrict__ kpe, float* __restrict__ kpT,
    float* __restrict__ kp_part, int N, int Npad)
{
    __shared__ float psum[120];
    int tid = threadIdx.x;
    if (tid < 120) psum[tid] = 0.f;
    float mxk[NH];
    #pragma unroll
    for (int hh=0;hh<NH;hh++) mxk[hh] = ord2f(mxk_u[hh]);
    __syncthreads();
    int n0 = blockIdx.x * 128;
    for (int r = 0; r < 60; r++) {
        int idx = r*256 + tid;
        int nl = idx / 120, hm = idx % 120;
        int n = n0 + nl;
        if (n >= N) break;
        int hh = hm/30, m = hm%30;
        float val = RATIO * (__expf(dd_k[(size_t)hh*N*NM + (size_t)n*NM + m]
                                    - diag_k[n*4+hh] - mxk[hh]) + EPSF);
        kpe[(size_t)n*128 + hm] = f2bf(val);
        kpT[((size_t)(hh*32+m))*Npad + n] = val;
        atomicAdd(&psum[hm], val);
    }
    __syncthreads();
    if (tid < 120) kp_part[blockIdx.x*120 + tid] = psum[tid];
}

__global__ void k_kpsred(const float* __restrict__ kp_part, float* __restrict__ kp_sum, int nblk){
    int t = threadIdx.x;
    if (t < 120) {
        float s = 0.f;
        for (int b=0;b<nblk;b++) s += kp_part[b*120+t];
        kp_sum[t] = s;
    }
}

// ---------------------------------------------------------------------------
// K-eg: egT[hk][n] = exp(gum[n][hk]), zero tail.
// ---------------------------------------------------------------------------
__global__ __launch_bounds__(256) void k_eg(const float* __restrict__ gum,
    float* __restrict__ egT, int N, int Npad)
{
    int n0 = blockIdx.x*64;
    for (int i = threadIdx.x; i < 64*40; i += 256){
        int nl = i / 40, hk = i % 40;
        int n = n0 + nl;
        if (n >= Npad) continue;
        float v = (n < N) ? __expf(gum[(size_t)n*40 + hk]) : 0.f;
        egT[(size_t)hk*Npad + n] = v;
    }
}

// ---------------------------------------------------------------------------
// K3: kvs via MFMA.  Block = (seg, h), 4 waves; wave owns 80 (k,m)-rows.
// ---------------------------------------------------------------------------
__global__ __launch_bounds__(256,1) void k_kvs2(const float* __restrict__ kpT,
    const float* __restrict__ egT, const ushort* __restrict__ vT16,
    float* __restrict__ part, int Npad)
{
    int seg = blockIdx.x, hh = blockIdx.y;
    int w = threadIdx.x >> 6, lane = threadIdx.x & 63;
    int l15 = lane & 15, lg = lane >> 4;
    int steps_total = Npad/32;
    int per = (steps_total + NSEG-1)/NSEG;
    int s0 = seg*per, s1 = min(steps_total, s0+per);

    const ushort* vbase = vT16 + (size_t)hh*64*Npad;
    const float* kpbase = kpT + (size_t)hh*32*Npad;
    const float* egbase = egT + (size_t)hh*10*Npad;

    f32x4 acc[5][4];
    #pragma unroll
    for (int mt=0;mt<5;mt++)
        #pragma unroll
        for (int nt=0;nt<4;nt++) acc[mt][nt] = (f32x4){0.f,0.f,0.f,0.f};

    for (int st = s0; st < s1; ++st){
        int n0 = st*32 + lg*8;
        s16x8 bf[4];
        #pragma unroll
        for (int nt=0;nt<4;nt++){
            uint4 u = *(const uint4*)(vbase + (size_t)(nt*16 + l15)*Npad + n0);
            bf[nt] = __builtin_bit_cast(s16x8, u);
        }
        #pragma unroll
        for (int mt=0;mt<5;mt++){
            int r = w*80 + mt*16 + l15;
            int m = r & 31, kk = r >> 5;
            const float* kprow = kpbase + (size_t)m*Npad;
            const float* egrow = egbase + (size_t)kk*Npad;
            f32x4 kp0 = *(const f32x4*)(kprow + n0);
            f32x4 kp1 = *(const f32x4*)(kprow + n0 + 4);
            f32x4 eg0 = *(const f32x4*)(egrow + n0);
            f32x4 eg1 = *(const f32x4*)(egrow + n0 + 4);
            f32x4 pr0 = kp0*eg0, pr1 = kp1*eg1;
            unsigned hi[8], lo[8];
            #pragma unroll
            for (int j=0;j<4;j++){
                bfsplit(pr0[j], hi[j], lo[j]);
                bfsplit(pr1[j], hi[4+j], lo[4+j]);
            }
            uint4 ahu, alu;
            ahu.x = hi[0]|(hi[1]<<16); ahu.y = hi[2]|(hi[3]<<16);
            ahu.z = hi[4]|(hi[5]<<16); ahu.w = hi[6]|(hi[7]<<16);
            alu.x = lo[0]|(lo[1]<<16); alu.y = lo[2]|(lo[3]<<16);
            alu.z = lo[4]|(lo[5]<<16); alu.w = lo[6]|(lo[7]<<16);
            s16x8 ah = __builtin_bit_cast(s16x8, ahu);
            s16x8 al = __builtin_bit_cast(s16x8, alu);
            #pragma unroll
            for (int nt=0;nt<4;nt++){
                acc[mt][nt] = __builtin_amdgcn_mfma_f32_16x16x32_bf16(al, bf[nt], acc[mt][nt], 0,0,0);
                acc[mt][nt] = __builtin_amdgcn_mfma_f32_16x16x32_bf16(ah, bf[nt], acc[mt][nt], 0,0,0);
            }
        }
    }
    float* dst = part + ((size_t)hh*NSEG + seg)*20480;
    #pragma unroll
    for (int mt=0;mt<5;mt++)
        #pragma unroll
        for (int nt=0;nt<4;nt++)
            #pragma unroll
            for (int i=0;i<4;i++){
                int rr = w*80 + mt*16 + lg*4 + i;
                dst[rr*64 + nt*16 + l15] = acc[mt][nt][i];
            }
}

__global__ void k_kvsred2(const float* __restrict__ part, float* __restrict__ kvs){
    int o = blockIdx.x*256 + threadIdx.x;   // 76800 = 4h*10k*30m*64d
    if (o >= 76800) return;
    int hh = o / 19200, r = o % 19200;
    int km = r >> 6, d = r & 63;
    int kk = km / 30, m = km % 30;
    size_t base = (size_t)hh*NSEG*20480 + (size_t)(kk*32+m)*64 + d;
    float s = 0.f;
    for (int sg=0; sg<NSEG; sg++) s += part[base + (size_t)sg*20480];
    kvs[o] = s;
}

// ---------------------------------------------------------------------------
// kg_sum = sum_n kpT*egT (f32 exact), partials over NSEG2 segments.
// ---------------------------------------------------------------------------
__global__ __launch_bounds__(320) void k_kgp(const float* __restrict__ kpT,
    const float* __restrict__ egT, float* __restrict__ kg_part, int Npad)
{
    int s2 = blockIdx.x, hh = blockIdx.y;
    int t = threadIdx.x;
    int kk = t >> 5, m = t & 31;
    int len = Npad / NSEG2;
    int n0 = s2*len;
    float acc = 0.f;
    if (kk < NK && m < NM){
        const f32x4* kr = (const f32x4*)(kpT + ((size_t)(hh*32+m))*Npad + n0);
        const f32x4* er = (const f32x4*)(egT + ((size_t)(hh*10+kk))*Npad + n0);
        for (int i=0;i<len/4;i++){
            f32x4 a = kr[i], b = er[i];
            acc = fmaf(a.x, b.x, acc); acc = fmaf(a.y, b.y, acc);
            acc = fmaf(a.z, b.z, acc); acc = fmaf(a.w, b.w, acc);
        }
    }
    kg_part[((size_t)hh*NSEG2 + s2)*320 + t] = acc;
}

__global__ void k_kgred2(const float* __restrict__ kg_part, float* __restrict__ kg_sum){
    int o = blockIdx.x*64 + threadIdx.x;   // 1200
    if (o >= 1200) return;
    int hh = o / 300, r = o % 300;
    int kk = r / 30, m = r % 30;
    float s = 0.f;
    for (int i=0;i<NSEG2;i++) s += kg_part[((size_t)hh*NSEG2 + i)*320 + kk*32 + m];
    kg_sum[o] = s;
}

// ---------------------------------------------------------------------------
// K4: WK panels = kvs @ Wo folded, in MFMA B-frag layout, bf16 hi/lo.
// Block = kstep (h*10+kq), 40 blocks.  WK[h][kq*32+m][dout], m>=30 -> 0.
// ---------------------------------------------------------------------------
__global__ __launch_bounds__(256) void k_wkprep(const float* __restrict__ kvs,
    const float* __restrict__ Wo, ushort* __restrict__ WKf_h, ushort* __restrict__ WKf_l)
{
    __shared__ float kv_s[30*65];
    __shared__ float wo_s[64*64];
    __shared__ float wks[32*64];
    int ks = blockIdx.x;
    int h = ks/10, kq = ks%10;
    int tid = threadIdx.x;
    for (int i=tid;i<1920;i+=256){ int m=i>>6, d=i&63; kv_s[m*65+d] = kvs[(size_t)h*19200 + (size_t)(kq*30)*64 + i]; }
    for (int i=tid;i<4096;i+=256) wo_s[i] = Wo[(size_t)h*64*64 + i];
    __syncthreads();
    int m = tid>>3, c0 = (tid&7)*8;
    float acc[8] = {0,0,0,0,0,0,0,0};
    if (m < 30){
        for (int d=0; d<64; d++){
            float kv = kv_s[m*65+d];
            const float* wr = &wo_s[d*64 + c0];
            #pragma unroll
            for (int j=0;j<8;j++) acc[j] = fmaf(kv, wr[j], acc[j]);
        }
    }
    #pragma unroll
    for (int j=0;j<8;j++) wks[m*64 + c0 + j] = acc[j];
    __syncthreads();
    int nt = tid>>6, lane = tid&63, l15 = lane&15, lg = lane>>4;
    unsigned hi[8], lo[8];
    #pragma unroll
    for (int jj=0;jj<8;jj++){
        float v = wks[(lg*8+jj)*64 + nt*16 + l15];
        bfsplit(v, hi[jj], lo[jj]);
    }
    uint4 ph, pl;
    ph.x = hi[0]|(hi[1]<<16); ph.y = hi[2]|(hi[3]<<16); ph.z = hi[4]|(hi[5]<<16); ph.w = hi[6]|(hi[7]<<16);
    pl.x = lo[0]|(lo[1]<<16); pl.y = lo[2]|(lo[3]<<16); pl.z = lo[4]|(lo[5]<<16); pl.w = lo[6]|(lo[7]<<16);
    size_t off = ((size_t)ks*4 + nt)*64 + lane;
    ((uint4*)WKf_h)[off] = ph;
    ((uint4*)WKf_l)[off] = pl;
}

// ---------------------------------------------------------------------------
// K5: out = qps @ WK + bias via MFMA (K=1280).  64 nodes/block, 4 waves.
// Also writes den into qpe row tail for k_edge.
// ---------------------------------------------------------------------------
__global__ __launch_bounds__(256) void k_zo(const float* __restrict__ qp,
    const ushort* __restrict__ WKf_h, const ushort* __restrict__ WKf_l,
    const float* __restrict__ kg_sum, const float* __restrict__ kp_sum,
    const float* __restrict__ Wob, ushort* __restrict__ qpe,
    float* __restrict__ out, int N)
{
    __shared__ float kg_s[1200];
    __shared__ float kps_s[120];
    __shared__ uint4 bs[2][2][256];   // [buf][hi/lo][nt*64+lane]
    int tid = threadIdx.x;
    int w = tid>>6, lane = tid&63, l15 = lane&15, lg = lane>>4;
    int n0 = blockIdx.x*64;
    int n = n0 + w*16 + l15;
    bool nv = (n < N);
    int nc = nv ? n : (N-1);

    for (int i=tid;i<1200;i+=256) kg_s[i] = kg_sum[i];
    if (tid < 120) kps_s[tid] = kp_sum[tid];
    // stage kstep 0
    {
        const uint4* sH = (const uint4*)WKf_h;
        const uint4* sL = (const uint4*)WKf_l;
        bs[0][0][tid] = sH[tid];
        bs[0][1][tid] = sL[tid];
    }

    // qA[h][jj]: this lane's m-slice (m = lg*8+jj) of qp row, per head
    float qA[4][8];
    const float* qrow = qp + (size_t)nc*120;
    #pragma unroll
    for (int h=0;h<4;h++)
      #pragma unroll
      for (int jj=0;jj<8;jj++){
        int m = lg*8+jj;
        qA[h][jj] = (m<30) ? qrow[h*30+m] : 0.f;
      }
    __syncthreads();

    // den_node -> qpe tail
    #pragma unroll
    for (int h=0;h<4;h++){
      float p = 0.f;
      #pragma unroll
      for (int jj=0;jj<8;jj++){
        int m = lg*8+jj;
        if (m<30) p = fmaf(qA[h][jj], kps_s[h*30+m], p);
      }
      p += __shfl_xor(p,16);
      p += __shfl_xor(p,32);
      if (lg==0 && nv) ((float*)qpe)[(size_t)n*64 + 60 + h] = p;
    }

    f32x4 acc[4];
    #pragma unroll
    for (int nt=0;nt<4;nt++) acc[nt] = (f32x4){0.f,0.f,0.f,0.f};

    #pragma unroll
    for (int h=0;h<4;h++){
      for (int kq=0;kq<10;kq++){
        int ks = h*10+kq;
        int buf = ks&1;
        if (ks < 39){
            const uint4* sH = (const uint4*)WKf_h + (size_t)(ks+1)*256;
            const uint4* sL = (const uint4*)WKf_l + (size_t)(ks+1)*256;
            bs[buf^1][0][tid] = sH[tid];
            bs[buf^1][1][tid] = sL[tid];
        }
        // scale = 0.1/z_den for (n, h, kq)
        float p = 0.f;
        #pragma unroll
        for (int jj=0;jj<8;jj++){
          int m = lg*8+jj;
          if (m<30) p = fmaf(qA[h][jj], kg_s[h*300 + kq*30 + m], p);
        }
        p += __shfl_xor(p,16);
        p += __shfl_xor(p,32);
        float sc = 0.1f / p;
        // A frag = qA[h]*sc, split hi/lo
        unsigned hi[8], lo[8];
        #pragma unroll
        for (int jj=0;jj<8;jj++) bfsplit(qA[h][jj]*sc, hi[jj], lo[jj]);
        uint4 ahu, alu;
        ahu.x = hi[0]|(hi[1]<<16); ahu.y = hi[2]|(hi[3]<<16);
        ahu.z = hi[4]|(hi[5]<<16); ahu.w = hi[6]|(hi[7]<<16);
        alu.x = lo[0]|(lo[1]<<16); alu.y = lo[2]|(lo[3]<<16);
        alu.z = lo[4]|(lo[5]<<16); alu.w = lo[6]|(lo[7]<<16);
        s16x8 ah = __builtin_bit_cast(s16x8, ahu);
        s16x8 al = __builtin_bit_cast(s16x8, alu);
        #pragma unroll
        for (int nt=0;nt<4;nt++){
            s16x8 bh = __builtin_bit_cast(s16x8, bs[buf][0][nt*64+lane]);
            s16x8 bl = __builtin_bit_cast(s16x8, bs[buf][1][nt*64+lane]);
            acc[nt] = __builtin_amdgcn_mfma_f32_16x16x32_bf16(ah, bl, acc[nt], 0,0,0);
            acc[nt] = __builtin_amdgcn_mfma_f32_16x16x32_bf16(al, bh, acc[nt], 0,0,0);
            acc[nt] = __builtin_amdgcn_mfma_f32_16x16x32_bf16(ah, bh, acc[nt], 0,0,0);
        }
        __syncthreads();
      }
    }

    // epilogue: C row = node (lg*4+i), col = dout (nt*16+l15)
    #pragma unroll
    for (int nt=0;nt<4;nt++){
        float bias = Wob[nt*16 + l15];
        #pragma unroll
        for (int i=0;i<4;i++){
            int node = n0 + w*16 + lg*4 + i;
            if (node < N) out[(size_t)node*64 + nt*16 + l15] = acc[nt][i] + bias;
        }
    }
}

// ---------------------------------------------------------------------------
// K7: edge attention weights (bf16 256B rows; den in qpe row tail).
// ---------------------------------------------------------------------------
__global__ __launch_bounds__(256) void k_edge(const int* __restrict__ ei,
    const ushort* __restrict__ qpe, const ushort* __restrict__ kpe,
    float* __restrict__ A, int E)
{
    int e = blockIdx.x*256 + threadIdx.x;
    if (e >= E) return;
    int s = ei[e], t = ei[E + e];
    const uint4* rq = (const uint4*)(qpe + (size_t)t*128);
    const uint4* rk = (const uint4*)(kpe + (size_t)s*128);
    float num[NH] = {0.f,0.f,0.f,0.f};
    #define ACC2(au,bu,idx0) { \
        float a0=__uint_as_float((au)<<16),        b0=__uint_as_float((bu)<<16); \
        float a1=__uint_as_float((au)&0xffff0000u),b1=__uint_as_float((bu)&0xffff0000u); \
        num[(idx0)/30]     = fmaf(a0,b0,num[(idx0)/30]); \
        num[((idx0)+1)/30] = fmaf(a1,b1,num[((idx0)+1)/30]); }
    #pragma unroll
    for (int j=0;j<15;j++){
        uint4 a = rq[j], b = rk[j];
        ACC2(a.x, b.x, j*8+0)
        ACC2(a.y, b.y, j*8+2)
        ACC2(a.z, b.z, j*8+4)
        ACC2(a.w, b.w, j*8+6)
    }
    #undef ACC2
    float4 dn = *(const float4*)((const float*)qpe + (size_t)t*64 + 60);
    float4 res = make_float4(num[0]/dn.x, num[1]/dn.y, num[2]/dn.z, num[3]/dn.w);
    *(float4*)(A + (size_t)e*4) = res;
}

// ---------------------------------------------------------------------------
extern "C" void kernel_launch(void* const* d_in, const int* in_sizes, int n_in,
                              void* d_out, int out_size, void* d_ws, size_t ws_size,
                              hipStream_t stream)
{
    const float* z    = (const float*)d_in[0];
    const int*   ei   = (const int*)d_in[1];
    const float* gum  = (const float*)d_in[2];
    const float* proj = (const float*)d_in[3];
    const float* Wq   = (const float*)d_in[4];
    const float* bq   = (const float*)d_in[5];
    const float* Wk   = (const float*)d_in[6];
    const float* bk   = (const float*)d_in[7];
    const float* Wv   = (const float*)d_in[8];
    const float* bv   = (const float*)d_in[9];
    const float* Wo   = (const float*)d_in[10];
    const float* Wob  = (const float*)d_in[11];
    int N = in_sizes[0] / NC;
    int E = in_sizes[1] / 2;
    int Npad = (N + 511) & ~511;

    float* ws = (float*)d_ws;
    size_t o = 0;
    #define ALIGN64 o = (o + 63) & ~(size_t)63;
    float* qp       = ws + o; o += (size_t)N*120;
    ALIGN64
    float* vbuf     = ws + o; o += (size_t)N*NHD;
    ALIGN64
    float* dd_k     = ws + o; o += (size_t)NH*N*NM;      // later: egT + kvs_part2
    float* egT      = dd_k;                              // 40*Npad
    float* kvs_part = dd_k + (size_t)40*Npad;            // NSEG*4*20480 fits
    ALIGN64
    float* diag_k   = ws + o; o += (size_t)N*4;
    unsigned* mxk_u = (unsigned*)(ws + o); o += 4;
    ALIGN64
    int nkb = (N+127)/128;
    float* kp_part  = ws + o; o += (size_t)nkb*120;
    float* kp_sum   = ws + o; o += 120;
    ALIGN64
    float* kg_part  = ws + o; o += (size_t)NH*NSEG2*320;
    float* kvs      = ws + o; o += 76800;
    float* kg_sum   = ws + o; o += 1200;
    ALIGN64
    ushort* qpe     = (ushort*)(ws + o); o += (size_t)N*64;
    ALIGN64
    ushort* kpe     = (ushort*)(ws + o); o += (size_t)N*64;
    ALIGN64
    ushort* Wt_h    = (ushort*)(ws + o); o += 48*4*64*8/2;
    ALIGN64
    ushort* Wt_l    = (ushort*)(ws + o); o += 48*4*64*8/2;
    ALIGN64
    float* kpT      = ws + o; o += (size_t)128*Npad;
    ALIGN64
    ushort* WKf_h   = (ushort*)(ws + o); o += 40*4*64*8/2;   // 81920 ushorts
    ALIGN64
    ushort* WKf_l   = (ushort*)(ws + o); o += 40*4*64*8/2;
    ushort* vT16    = (ushort*)vbuf;                     // dead after k_kvs2

    float* out = (float*)d_out;
    float* A   = out + (size_t)N*ND;

    k_wprep<<<dim3(48), dim3(256), 0, stream>>>(Wq, Wk, Wv, Wt_h, Wt_l);
    k_init<<<dim3(1), dim3(64), 0, stream>>>(mxk_u);
    {
        int tail = Npad - N;
        int zwork = 8*Npad + (128+256)*tail;
        k_zfill<<<dim3((zwork+255)/256), dim3(256), 0, stream>>>(kpT, vT16, N, Npad);
    }
    k_qkv<<<dim3((N+15)/16), dim3(256), 0, stream>>>(z, Wt_h, Wt_l, bq, bk, bv, proj,
                                                     qp, qpe, dd_k, diag_k, vT16, N, Npad);
    k_maxred<<<dim3(48,4), dim3(256), 0, stream>>>(dd_k, mxk_u, N);
    k_kp<<<dim3(nkb), dim3(256), 0, stream>>>(dd_k, diag_k, mxk_u, kpe, kpT, kp_part, N, Npad);
    k_kpsred<<<dim3(1), dim3(128), 0, stream>>>(kp_part, kp_sum, nkb);
    k_eg<<<dim3(Npad/64), dim3(256), 0, stream>>>(gum, egT, N, Npad);
    k_kvs2<<<dim3(NSEG, NH), dim3(256), 0, stream>>>(kpT, egT, vT16, kvs_part, Npad);
    k_kgp<<<dim3(NSEG2, NH), dim3(320), 0, stream>>>(kpT, egT, kg_part, Npad);
    k_kvsred2<<<dim3(300), dim3(256), 0, stream>>>(kvs_part, kvs);
    k_kgred2<<<dim3(19), dim3(64), 0, stream>>>(kg_part, kg_sum);
    k_wkprep<<<dim3(40), dim3(256), 0, stream>>>(kvs, Wo, WKf_h, WKf_l);
    k_zo<<<dim3((N+63)/64), dim3(256), 0, stream>>>(qp, WKf_h, WKf_l, kg_sum, kp_sum,
                                                    Wob, qpe, out, N);
    k_edge<<<dim3((E+255)/256), dim3(256), 0, stream>>>(ei, qpe, kpe, A, E);
}

// Round 6
// 588.058 us; speedup vs baseline: 2.5411x; 1.2034x over previous
//
#include <hip/hip_runtime.h>
#include <math.h>

#define NH 4
#define ND 64
#define NC 128
#define NHD 256
#define NM 30
#define NK 10
#define EPSF 1e-6f
#define RATIO 0.18257418583505536f    // 1/sqrt(30)
#define QKSCALE 0.7071067811865476f   // inv_sqrt_tau(=2) * 64^{-1/4}(=0.353553)
#define NSEG 48                       // kvs2 n-segments (blocks = NSEG*NH)
#define NSEG2 128                     // kg_sum partial segments

typedef float f32x4 __attribute__((ext_vector_type(4)));
typedef short s16x8 __attribute__((ext_vector_type(8)));

__device__ __forceinline__ unsigned f2ord(float f){ unsigned b=__float_as_uint(f); return (b&0x80000000u)?~b:(b|0x80000000u); }
__device__ __forceinline__ float ord2f(unsigned u){ return __uint_as_float((u&0x80000000u)?(u&0x7fffffffu):~u); }
// round-to-nearest-even f32 -> bf16 (finite values)
__device__ __forceinline__ ushort f2bf(float f){ unsigned b=__float_as_uint(f); return (ushort)((b + 0x7fffu + ((b>>16)&1u))>>16); }
__device__ __forceinline__ float bf2f(ushort u){ return __uint_as_float(((unsigned)u)<<16); }
// split f32 -> bf16 hi + bf16 lo (hi+lo ~= p to 2^-17 rel)
__device__ __forceinline__ void bfsplit(float p, unsigned& hi, unsigned& lo){
    unsigned pb = __float_as_uint(p);
    unsigned t  = pb + 0x8000u;
    unsigned hf = t & 0xffff0000u;
    hi = t >> 16;
    lo = __float_as_uint(p - __uint_as_float(hf)) >> 16;
}

__global__ void k_init(unsigned* mxk_u){ if (threadIdx.x < NH) mxk_u[threadIdx.x] = 0u; }

// ---------------------------------------------------------------------------
// K0: prep W (q|k|v concat, 768 cols) into MFMA B-fragment layout, bf16 hi/lo.
// ---------------------------------------------------------------------------
__global__ __launch_bounds__(256) void k_wprep(const float* __restrict__ Wq,
    const float* __restrict__ Wk, const float* __restrict__ Wv,
    ushort* __restrict__ Wt_h, ushort* __restrict__ Wt_l)
{
    int idx = blockIdx.x*256 + threadIdx.x;   // 48*4*64 = 12288
    if (idx >= 48*4*64) return;
    int lane = idx & 63, ks = (idx>>6)&3, tile = idx>>8;
    int c = tile*16 + (lane&15);
    int k0 = ks*32 + (lane>>4)*8;
    const float* W; int cc;
    if (c < 256)      { W = Wq; cc = c; }
    else if (c < 512) { W = Wk; cc = c-256; }
    else              { W = Wv; cc = c-512; }
    #pragma unroll
    for (int j=0;j<8;j++){
        float w = W[(size_t)(k0+j)*NHD + cc];
        ushort h = f2bf(w);
        Wt_h[(size_t)idx*8+j] = h;
        Wt_l[(size_t)idx*8+j] = f2bf(w - bf2f(h));
    }
}

// ---------------------------------------------------------------------------
// K0b: prep proj into dd B-frag layout: pf[kt(2)][ct(2)][lane(64)][j(8)], hi/lo.
// m = ct*16+(lane&15) (m>=30 -> 0), k=d = kt*32+(lane>>4)*8+j.
// ---------------------------------------------------------------------------
__global__ __launch_bounds__(256) void k_pprep(const float* __restrict__ proj,
    ushort* __restrict__ pf_h, ushort* __restrict__ pf_l)
{
    int tid = threadIdx.x;
    int lane = tid & 63, ct = (tid>>6)&1, kt = tid>>7;
    int m = ct*16 + (lane&15);
    int d0 = kt*32 + (lane>>4)*8;
    #pragma unroll
    for (int j=0;j<8;j++){
        float v = (m < NM) ? proj[(size_t)m*ND + d0 + j] : 0.f;
        unsigned hi, lo; bfsplit(v, hi, lo);
        size_t off = ((size_t)((kt*2+ct)*64+lane))*8 + j;
        pf_h[off] = (ushort)hi;
        pf_l[off] = (ushort)lo;
    }
}

// ---------------------------------------------------------------------------
// K-zfill: zero kpT pad rows (m=30,31), kpT row tails, vT16 row tails.
// ---------------------------------------------------------------------------
__global__ __launch_bounds__(256) void k_zfill(float* __restrict__ kpT,
    ushort* __restrict__ vT16, int N, int Npad)
{
    int tail = Npad - N;
    int w1 = 8*Npad, w2 = 128*tail, w3 = 256*tail;
    int idx = blockIdx.x*256 + threadIdx.x;
    if (idx < w1){
        int r = idx / Npad, c = idx % Npad;
        int hh = r>>1, m = 30 + (r&1);
        kpT[((size_t)(hh*32+m))*Npad + c] = 0.f;
    } else if (idx < w1+w2){
        int j = idx - w1; int r = j / tail, c = N + j % tail;
        kpT[(size_t)r*Npad + c] = 0.f;
    } else if (idx < w1+w2+w3){
        int j = idx - w1 - w2; int r = j / tail, c = N + j % tail;
        vT16[(size_t)r*Npad + c] = 0;
    }
}

// ---------------------------------------------------------------------------
// K1: QKV projection via 3-pass split-bf16 MFMA; dd via MFMA (x and proj both
// hi/lo split); v direct to vT16; qp computed in-kernel.  16 nodes/block.
// ---------------------------------------------------------------------------
__global__ __launch_bounds__(256) void k_qkv(
    const float* __restrict__ z,
    const ushort* __restrict__ Wt_h, const ushort* __restrict__ Wt_l,
    const float* __restrict__ bq, const float* __restrict__ bk,
    const float* __restrict__ bv,
    const ushort* __restrict__ pf_h, const ushort* __restrict__ pf_l,
    float* __restrict__ qp, ushort* __restrict__ qpe,
    float* __restrict__ dd_k, float* __restrict__ diag_k,
    ushort* __restrict__ vT16, int N, int Npad)
{
    __shared__ unsigned xs[8*16*68];   // 34.8 KB  packed (hi<<16)|lo per x element
    __shared__ float pq[4*16*33];      // 8.25 KB  raw dd for q-pairs
    __shared__ float diagq[4*16];
    __shared__ float mxs[4*16];
    int tid = threadIdx.x;
    int n0 = blockIdx.x * 16;
    int w = tid >> 6, lane = tid & 63;
    int l15 = lane & 15, kgrp = lane >> 4;

    // ---- A fragments (z rows), split bf16 hi/lo ----
    int nn = n0 + l15; if (nn > N-1) nn = N-1;
    const float* zrow = z + (size_t)nn*NC;
    s16x8 ah[4], al[4];
    #pragma unroll
    for (int ks=0;ks<4;ks++){
        f32x4 f0 = *(const f32x4*)(zrow + ks*32 + kgrp*8);
        f32x4 f1 = *(const f32x4*)(zrow + ks*32 + kgrp*8 + 4);
        #pragma unroll
        for (int j=0;j<4;j++){
            float v0 = f0[j]; ushort h0 = f2bf(v0);
            ah[ks][j]   = (short)h0; al[ks][j]   = (short)f2bf(v0 - bf2f(h0));
            float v1 = f1[j]; ushort h1 = f2bf(v1);
            ah[ks][4+j] = (short)h1; al[ks][4+j] = (short)f2bf(v1 - bf2f(h1));
        }
    }

    // ---- phase 1: MFMA over 12 col-tiles per wave ----
    const uint4* WH = (const uint4*)Wt_h;
    const uint4* WL = (const uint4*)Wt_l;
    for (int nt=0; nt<12; nt++){
        int tile = w*12 + nt;
        f32x4 acc = {0.f,0.f,0.f,0.f};
        #pragma unroll
        for (int ks=0;ks<4;ks++){
            uint4 bhu = WH[(size_t)(tile*4+ks)*64 + lane];
            uint4 blu = WL[(size_t)(tile*4+ks)*64 + lane];
            s16x8 bh = __builtin_bit_cast(s16x8, bhu);
            s16x8 bl = __builtin_bit_cast(s16x8, blu);
            acc = __builtin_amdgcn_mfma_f32_16x16x32_bf16(ah[ks], bl, acc, 0,0,0);
            acc = __builtin_amdgcn_mfma_f32_16x16x32_bf16(al[ks], bh, acc, 0,0,0);
            acc = __builtin_amdgcn_mfma_f32_16x16x32_bf16(ah[ks], bh, acc, 0,0,0);
        }
        int c = tile*16 + l15;
        if (c < 512) {
            int qk = c >> 8, ccc = c & 255;
            float bias = (qk==0) ? bq[ccc] : bk[ccc];
            int hh = ccc>>6, d = ccc&63;
            int pair = qk*4 + hh;
            #pragma unroll
            for (int i=0;i<4;i++){
                int node = kgrp*4 + i;
                float x = (acc[i] + bias) * QKSCALE;
                unsigned hi, lo; bfsplit(x, hi, lo);
                xs[(pair*16 + node)*68 + d] = (hi<<16) | lo;
            }
        } else {
            int cv = c - 512;
            float bias = bv[cv];
            ushort t0 = f2bf(acc[0]+bias), t1 = f2bf(acc[1]+bias);
            ushort t2 = f2bf(acc[2]+bias), t3 = f2bf(acc[3]+bias);
            int nb = n0 + kgrp*4;
            ushort* dst = &vT16[(size_t)cv*Npad + nb];
            if (nb + 4 <= N) {
                uint2 pk;
                pk.x = (unsigned)t0 | ((unsigned)t1<<16);
                pk.y = (unsigned)t2 | ((unsigned)t3<<16);
                *(uint2*)dst = pk;
            } else {
                if (nb   < N) dst[0] = t0;
                if (nb+1 < N) dst[1] = t1;
                if (nb+2 < N) dst[2] = t2;
                if (nb+3 < N) dst[3] = t3;
            }
        }
    }
    __syncthreads();

    // ---- diag: tid<128 -> (pair, node) ----
    if (tid < 128){
        int pair = tid >> 4, node = tid & 15;
        const unsigned* xr = &xs[(pair*16+node)*68];
        float s = 0.f;
        #pragma unroll 8
        for (int d=0; d<ND; d++){
            unsigned u = xr[d];
            float x = bf2f((ushort)(u>>16)) + bf2f((ushort)(u&0xffffu));
            s = fmaf(x, x, s);
        }
        s *= 0.5f;
        int n = n0 + node;
        if (pair < 4) diagq[pair*16+node] = s;
        else if (n < N) diag_k[n*4 + (pair-4)] = s;
    }
    __syncthreads();

    // ---- dd via MFMA: 2 pairs per wave ----
    const uint4* PH = (const uint4*)pf_h;
    const uint4* PL = (const uint4*)pf_l;
    #pragma unroll
    for (int pi=0; pi<2; pi++){
        int pair = w*2 + pi;
        f32x4 accd[2];
        accd[0] = (f32x4){0.f,0.f,0.f,0.f};
        accd[1] = (f32x4){0.f,0.f,0.f,0.f};
        #pragma unroll
        for (int kt=0; kt<2; kt++){
            // A frag: x row = node l15, k = kt*32 + kgrp*8 + j
            const unsigned* xr = &xs[(pair*16 + l15)*68 + kt*32 + kgrp*8];
            unsigned x0 = xr[0], x1 = xr[1], x2 = xr[2], x3 = xr[3];
            unsigned x4 = xr[4], x5 = xr[5], x6 = xr[6], x7 = xr[7];
            uint4 ahu, alu;
            ahu.x = (x1 & 0xffff0000u) | (x0 >> 16);
            ahu.y = (x3 & 0xffff0000u) | (x2 >> 16);
            ahu.z = (x5 & 0xffff0000u) | (x4 >> 16);
            ahu.w = (x7 & 0xffff0000u) | (x6 >> 16);
            alu.x = (x1 << 16) | (x0 & 0xffffu);
            alu.y = (x3 << 16) | (x2 & 0xffffu);
            alu.z = (x5 << 16) | (x4 & 0xffffu);
            alu.w = (x7 << 16) | (x6 & 0xffffu);
            s16x8 xah = __builtin_bit_cast(s16x8, ahu);
            s16x8 xal = __builtin_bit_cast(s16x8, alu);
            #pragma unroll
            for (int ct=0; ct<2; ct++){
                uint4 bhu = PH[(size_t)(kt*2+ct)*64 + lane];
                uint4 blu = PL[(size_t)(kt*2+ct)*64 + lane];
                s16x8 bh = __builtin_bit_cast(s16x8, bhu);
                s16x8 bl = __builtin_bit_cast(s16x8, blu);
                accd[ct] = __builtin_amdgcn_mfma_f32_16x16x32_bf16(xah, bl, accd[ct], 0,0,0);
                accd[ct] = __builtin_amdgcn_mfma_f32_16x16x32_bf16(xal, bh, accd[ct], 0,0,0);
                accd[ct] = __builtin_amdgcn_mfma_f32_16x16x32_bf16(xah, bh, accd[ct], 0,0,0);
            }
        }
        // epilogue: col m = ct*16+l15, row node = kgrp*4+i
        if (pair < 4){
            #pragma unroll
            for (int ct=0; ct<2; ct++)
                #pragma unroll
                for (int i=0;i<4;i++)
                    pq[(pair*16 + kgrp*4+i)*33 + ct*16 + l15] = accd[ct][i];
        } else {
            int hh = pair - 4;
            #pragma unroll
            for (int ct=0; ct<2; ct++){
                int m = ct*16 + l15;
                if (m < NM){
                    #pragma unroll
                    for (int i=0;i<4;i++){
                        int n = n0 + kgrp*4 + i;
                        if (n < N) dd_k[(size_t)hh*N*NM + (size_t)n*NM + m] = accd[ct][i];
                    }
                }
            }
        }
    }
    __syncthreads();

    // ---- per-(pair,node) max over m ----
    if (tid < 64){
        int pair = tid >> 4, node = tid & 15;
        const float* pr = &pq[(pair*16+node)*33];
        float mx = -3.0e38f;
        #pragma unroll
        for (int m=0;m<NM;m++) mx = fmaxf(mx, pr[m]);
        mxs[tid] = mx;
    }
    __syncthreads();

    // ---- qp = ratio*(exp(dd - diag - mx) + eps) ----
    for (int idx = tid; idx < 16*120; idx += 256){
        int node = idx / 120, hm = idx % 120;
        int n = n0 + node;
        if (n >= N) continue;
        int p = hm / 30, m = hm % 30;
        float val = RATIO * (__expf(pq[(p*16+node)*33 + m] - diagq[p*16+node] - mxs[p*16+node]) + EPSF);
        qp[(size_t)n*120 + hm] = val;
        qpe[(size_t)n*128 + hm] = f2bf(val);
    }
}

// ---------------------------------------------------------------------------
// K1.5: global max of dd_k per head
// ---------------------------------------------------------------------------
__global__ __launch_bounds__(256) void k_maxred(const float* __restrict__ dd_k,
                                                unsigned* __restrict__ mxk_u, int N)
{
    int hh = blockIdx.y;
    size_t len = (size_t)N*NM;
    const float* p = dd_k + (size_t)hh*len;
    float mx = -3.0e38f;
    for (size_t i = (size_t)blockIdx.x*256 + threadIdx.x; i < len; i += (size_t)gridDim.x*256)
        mx = fmaxf(mx, p[i]);
    for (int o=32;o>0;o>>=1) mx = fmaxf(mx, __shfl_down(mx, o));
    __shared__ float wmax[4];
    if ((threadIdx.x & 63) == 0) wmax[threadIdx.x >> 6] = mx;
    __syncthreads();
    if (threadIdx.x == 0) {
        mx = fmaxf(fmaxf(wmax[0],wmax[1]), fmaxf(wmax[2],wmax[3]));
        atomicMax(&mxk_u[hh], f2ord(mx));
    }
}

// ---------------------------------------------------------------------------
// K2: kp features -> kpe (bf16 edge rows), kpT (f32 transposed panel), partial sums.
// ---------------------------------------------------------------------------
__global__ __launch_bounds__(256) void k_kp(const float* __restrict__ dd_k,
    const float* __restrict__ diag_k, const unsigned* __restrict__ mxk_u,
    ushort* __restrict__ kpe, float* __restrict__ kpT,
    float* __restrict__ kp_part, int N, int Npad)
{
    __shared__ float psum[120];
    int tid = threadIdx.x;
    if (tid < 120) psum[tid] = 0.f;
    float mxk[NH];
    #pragma unroll
    for (int hh=0;hh<NH;hh++) mxk[hh] = ord2f(mxk_u[hh]);
    __syncthreads();
    int n0 = blockIdx.x * 128;
    for (int r = 0; r < 60; r++) {
        int idx = r*256 + tid;
        int nl = idx / 120, hm = idx % 120;
        int n = n0 + nl;
        if (n >= N) break;
        int hh = hm/30, m = hm%30;
        float val = RATIO * (__expf(dd_k[(size_t)hh*N*NM + (size_t)n*NM + m]
                                    - diag_k[n*4+hh] - mxk[hh]) + EPSF);
        kpe[(size_t)n*128 + hm] = f2bf(val);
        kpT[((size_t)(hh*32+m))*Npad + n] = val;
        atomicAdd(&psum[hm], val);
    }
    __syncthreads();
    if (tid < 120) kp_part[blockIdx.x*120 + tid] = psum[tid];
}

__global__ void k_kpsred(const float* __restrict__ kp_part, float* __restrict__ kp_sum, int nblk){
    int t = threadIdx.x;
    if (t < 120) {
        float s = 0.f;
        for (int b=0;b<nblk;b++) s += kp_part[b*120+t];
        kp_sum[t] = s;
    }
}

// ---------------------------------------------------------------------------
// K-eg: egT[hk][n] = exp(gum[n][hk]), zero tail.
// ---------------------------------------------------------------------------
__global__ __launch_bounds__(256) void k_eg(const float* __restrict__ gum,
    float* __restrict__ egT, int N, int Npad)
{
    int n0 = blockIdx.x*64;
    for (int i = threadIdx.x; i < 64*40; i += 256){
        int nl = i / 40, hk = i % 40;
        int n = n0 + nl;
        if (n >= Npad) continue;
        float v = (n < N) ? __expf(gum[(size_t)n*40 + hk]) : 0.f;
        egT[(size_t)hk*Npad + n] = v;
    }
}

// ---------------------------------------------------------------------------
// K3: kvs via MFMA.  Block = (seg, h), 4 waves; wave owns 80 (k,m)-rows.
// ---------------------------------------------------------------------------
__global__ __launch_bounds__(256,1) void k_kvs2(const float* __restrict__ kpT,
    const float* __restrict__ egT, const ushort* __restrict__ vT16,
    float* __restrict__ part, int Npad)
{
    int seg = blockIdx.x, hh = blockIdx.y;
    int w = threadIdx.x >> 6, lane = threadIdx.x & 63;
    int l15 = lane & 15, lg = lane >> 4;
    int steps_total = Npad/32;
    int per = (steps_total + NSEG-1)/NSEG;
    int s0 = seg*per, s1 = min(steps_total, s0+per);

    const ushort* vbase = vT16 + (size_t)hh*64*Npad;
    const float* kpbase = kpT + (size_t)hh*32*Npad;
    const float* egbase = egT + (size_t)hh*10*Npad;

    f32x4 acc[5][4];
    #pragma unroll
    for (int mt=0;mt<5;mt++)
        #pragma unroll
        for (int nt=0;nt<4;nt++) acc[mt][nt] = (f32x4){0.f,0.f,0.f,0.f};

    for (int st = s0; st < s1; ++st){
        int n0 = st*32 + lg*8;
        s16x8 bf[4];
        #pragma unroll
        for (int nt=0;nt<4;nt++){
            uint4 u = *(const uint4*)(vbase + (size_t)(nt*16 + l15)*Npad + n0);
            bf[nt] = __builtin_bit_cast(s16x8, u);
        }
        #pragma unroll
        for (int mt=0;mt<5;mt++){
            int r = w*80 + mt*16 + l15;
            int m = r & 31, kk = r >> 5;
            const float* kprow = kpbase + (size_t)m*Npad;
            const float* egrow = egbase + (size_t)kk*Npad;
            f32x4 kp0 = *(const f32x4*)(kprow + n0);
            f32x4 kp1 = *(const f32x4*)(kprow + n0 + 4);
            f32x4 eg0 = *(const f32x4*)(egrow + n0);
            f32x4 eg1 = *(const f32x4*)(egrow + n0 + 4);
            f32x4 pr0 = kp0*eg0, pr1 = kp1*eg1;
            unsigned hi[8], lo[8];
            #pragma unroll
            for (int j=0;j<4;j++){
                bfsplit(pr0[j], hi[j], lo[j]);
                bfsplit(pr1[j], hi[4+j], lo[4+j]);
            }
            uint4 ahu, alu;
            ahu.x = hi[0]|(hi[1]<<16); ahu.y = hi[2]|(hi[3]<<16);
            ahu.z = hi[4]|(hi[5]<<16); ahu.w = hi[6]|(hi[7]<<16);
            alu.x = lo[0]|(lo[1]<<16); alu.y = lo[2]|(lo[3]<<16);
            alu.z = lo[4]|(lo[5]<<16); alu.w = lo[6]|(lo[7]<<16);
            s16x8 ah = __builtin_bit_cast(s16x8, ahu);
            s16x8 al = __builtin_bit_cast(s16x8, alu);
            #pragma unroll
            for (int nt=0;nt<4;nt++){
                acc[mt][nt] = __builtin_amdgcn_mfma_f32_16x16x32_bf16(al, bf[nt], acc[mt][nt], 0,0,0);
                acc[mt][nt] = __builtin_amdgcn_mfma_f32_16x16x32_bf16(ah, bf[nt], acc[mt][nt], 0,0,0);
            }
        }
    }
    float* dst = part + ((size_t)hh*NSEG + seg)*20480;
    #pragma unroll
    for (int mt=0;mt<5;mt++)
        #pragma unroll
        for (int nt=0;nt<4;nt++)
            #pragma unroll
            for (int i=0;i<4;i++){
                int rr = w*80 + mt*16 + lg*4 + i;
                dst[rr*64 + nt*16 + l15] = acc[mt][nt][i];
            }
}

__global__ void k_kvsred2(const float* __restrict__ part, float* __restrict__ kvs){
    int o = blockIdx.x*256 + threadIdx.x;   // 76800 = 4h*10k*30m*64d
    if (o >= 76800) return;
    int hh = o / 19200, r = o % 19200;
    int km = r >> 6, d = r & 63;
    int kk = km / 30, m = km % 30;
    size_t base = (size_t)hh*NSEG*20480 + (size_t)(kk*32+m)*64 + d;
    float s = 0.f;
    for (int sg=0; sg<NSEG; sg++) s += part[base + (size_t)sg*20480];
    kvs[o] = s;
}

// ---------------------------------------------------------------------------
// kg_sum = sum_n kpT*egT (f32 exact), partials over NSEG2 segments.
// ---------------------------------------------------------------------------
__global__ __launch_bounds__(320) void k_kgp(const float* __restrict__ kpT,
    const float* __restrict__ egT, float* __restrict__ kg_part, int Npad)
{
    int s2 = blockIdx.x, hh = blockIdx.y;
    int t = threadIdx.x;
    int kk = t >> 5, m = t & 31;
    int len = Npad / NSEG2;
    int n0 = s2*len;
    float acc = 0.f;
    if (kk < NK && m < NM){
        const f32x4* kr = (const f32x4*)(kpT + ((size_t)(hh*32+m))*Npad + n0);
        const f32x4* er = (const f32x4*)(egT + ((size_t)(hh*10+kk))*Npad + n0);
        for (int i=0;i<len/4;i++){
            f32x4 a = kr[i], b = er[i];
            acc = fmaf(a.x, b.x, acc); acc = fmaf(a.y, b.y, acc);
            acc = fmaf(a.z, b.z, acc); acc = fmaf(a.w, b.w, acc);
        }
    }
    kg_part[((size_t)hh*NSEG2 + s2)*320 + t] = acc;
}

__global__ void k_kgred2(const float* __restrict__ kg_part, float* __restrict__ kg_sum){
    int o = blockIdx.x*64 + threadIdx.x;   // 1200
    if (o >= 1200) return;
    int hh = o / 300, r = o % 300;
    int kk = r / 30, m = r % 30;
    float s = 0.f;
    for (int i=0;i<NSEG2;i++) s += kg_part[((size_t)hh*NSEG2 + i)*320 + kk*32 + m];
    kg_sum[o] = s;
}

// ---------------------------------------------------------------------------
// K4: WK panels = kvs @ Wo folded, in MFMA B-frag layout, bf16 hi/lo.
// ---------------------------------------------------------------------------
__global__ __launch_bounds__(256) void k_wkprep(const float* __restrict__ kvs,
    const float* __restrict__ Wo, ushort* __restrict__ WKf_h, ushort* __restrict__ WKf_l)
{
    __shared__ float kv_s[30*65];
    __shared__ float wo_s[64*64];
    __shared__ float wks[32*64];
    int ks = blockIdx.x;
    int h = ks/10, kq = ks%10;
    int tid = threadIdx.x;
    for (int i=tid;i<1920;i+=256){ int m=i>>6, d=i&63; kv_s[m*65+d] = kvs[(size_t)h*19200 + (size_t)(kq*30)*64 + i]; }
    for (int i=tid;i<4096;i+=256) wo_s[i] = Wo[(size_t)h*64*64 + i];
    __syncthreads();
    int m = tid>>3, c0 = (tid&7)*8;
    float acc[8] = {0,0,0,0,0,0,0,0};
    if (m < 30){
        for (int d=0; d<64; d++){
            float kv = kv_s[m*65+d];
            const float* wr = &wo_s[d*64 + c0];
            #pragma unroll
            for (int j=0;j<8;j++) acc[j] = fmaf(kv, wr[j], acc[j]);
        }
    }
    #pragma unroll
    for (int j=0;j<8;j++) wks[m*64 + c0 + j] = acc[j];
    __syncthreads();
    int nt = tid>>6, lane = tid&63, l15 = lane&15, lg = lane>>4;
    unsigned hi[8], lo[8];
    #pragma unroll
    for (int jj=0;jj<8;jj++){
        float v = wks[(lg*8+jj)*64 + nt*16 + l15];
        bfsplit(v, hi[jj], lo[jj]);
    }
    uint4 ph, pl;
    ph.x = hi[0]|(hi[1]<<16); ph.y = hi[2]|(hi[3]<<16); ph.z = hi[4]|(hi[5]<<16); ph.w = hi[6]|(hi[7]<<16);
    pl.x = lo[0]|(lo[1]<<16); pl.y = lo[2]|(lo[3]<<16); pl.z = lo[4]|(lo[5]<<16); pl.w = lo[6]|(lo[7]<<16);
    size_t off = ((size_t)ks*4 + nt)*64 + lane;
    ((uint4*)WKf_h)[off] = ph;
    ((uint4*)WKf_l)[off] = pl;
}

// ---------------------------------------------------------------------------
// K5: out = qps @ WK + bias via MFMA (K=1280).  64 nodes/block, 4 waves.
// ---------------------------------------------------------------------------
__global__ __launch_bounds__(256) void k_zo(const float* __restrict__ qp,
    const ushort* __restrict__ WKf_h, const ushort* __restrict__ WKf_l,
    const float* __restrict__ kg_sum, const float* __restrict__ kp_sum,
    const float* __restrict__ Wob, ushort* __restrict__ qpe,
    float* __restrict__ out, int N)
{
    __shared__ float kg_s[1200];
    __shared__ float kps_s[120];
    __shared__ uint4 bs[2][2][256];
    int tid = threadIdx.x;
    int w = tid>>6, lane = tid&63, l15 = lane&15, lg = lane>>4;
    int n0 = blockIdx.x*64;
    int n = n0 + w*16 + l15;
    bool nv = (n < N);
    int nc = nv ? n : (N-1);

    for (int i=tid;i<1200;i+=256) kg_s[i] = kg_sum[i];
    if (tid < 120) kps_s[tid] = kp_sum[tid];
    {
        const uint4* sH = (const uint4*)WKf_h;
        const uint4* sL = (const uint4*)WKf_l;
        bs[0][0][tid] = sH[tid];
        bs[0][1][tid] = sL[tid];
    }

    float qA[4][8];
    const float* qrow = qp + (size_t)nc*120;
    #pragma unroll
    for (int h=0;h<4;h++)
      #pragma unroll
      for (int jj=0;jj<8;jj++){
        int m = lg*8+jj;
        qA[h][jj] = (m<30) ? qrow[h*30+m] : 0.f;
      }
    __syncthreads();

    #pragma unroll
    for (int h=0;h<4;h++){
      float p = 0.f;
      #pragma unroll
      for (int jj=0;jj<8;jj++){
        int m = lg*8+jj;
        if (m<30) p = fmaf(qA[h][jj], kps_s[h*30+m], p);
      }
      p += __shfl_xor(p,16);
      p += __shfl_xor(p,32);
      if (lg==0 && nv) ((float*)qpe)[(size_t)n*64 + 60 + h] = p;
    }

    f32x4 acc[4];
    #pragma unroll
    for (int nt=0;nt<4;nt++) acc[nt] = (f32x4){0.f,0.f,0.f,0.f};

    #pragma unroll
    for (int h=0;h<4;h++){
      for (int kq=0;kq<10;kq++){
        int ks = h*10+kq;
        int buf = ks&1;
        if (ks < 39){
            const uint4* sH = (const uint4*)WKf_h + (size_t)(ks+1)*256;
            const uint4* sL = (const uint4*)WKf_l + (size_t)(ks+1)*256;
            bs[buf^1][0][tid] = sH[tid];
            bs[buf^1][1][tid] = sL[tid];
        }
        float p = 0.f;
        #pragma unroll
        for (int jj=0;jj<8;jj++){
          int m = lg*8+jj;
          if (m<30) p = fmaf(qA[h][jj], kg_s[h*300 + kq*30 + m], p);
        }
        p += __shfl_xor(p,16);
        p += __shfl_xor(p,32);
        float sc = 0.1f / p;
        unsigned hi[8], lo[8];
        #pragma unroll
        for (int jj=0;jj<8;jj++) bfsplit(qA[h][jj]*sc, hi[jj], lo[jj]);
        uint4 ahu, alu;
        ahu.x = hi[0]|(hi[1]<<16); ahu.y = hi[2]|(hi[3]<<16);
        ahu.z = hi[4]|(hi[5]<<16); ahu.w = hi[6]|(hi[7]<<16);
        alu.x = lo[0]|(lo[1]<<16); alu.y = lo[2]|(lo[3]<<16);
        alu.z = lo[4]|(lo[5]<<16); alu.w = lo[6]|(lo[7]<<16);
        s16x8 ah = __builtin_bit_cast(s16x8, ahu);
        s16x8 al = __builtin_bit_cast(s16x8, alu);
        #pragma unroll
        for (int nt=0;nt<4;nt++){
            s16x8 bh = __builtin_bit_cast(s16x8, bs[buf][0][nt*64+lane]);
            s16x8 bl = __builtin_bit_cast(s16x8, bs[buf][1][nt*64+lane]);
            acc[nt] = __builtin_amdgcn_mfma_f32_16x16x32_bf16(ah, bl, acc[nt], 0,0,0);
            acc[nt] = __builtin_amdgcn_mfma_f32_16x16x32_bf16(al, bh, acc[nt], 0,0,0);
            acc[nt] = __builtin_amdgcn_mfma_f32_16x16x32_bf16(ah, bh, acc[nt], 0,0,0);
        }
        __syncthreads();
      }
    }

    #pragma unroll
    for (int nt=0;nt<4;nt++){
        float bias = Wob[nt*16 + l15];
        #pragma unroll
        for (int i=0;i<4;i++){
            int node = n0 + w*16 + lg*4 + i;
            if (node < N) out[(size_t)node*64 + nt*16 + l15] = acc[nt][i] + bias;
        }
    }
}

// ---------------------------------------------------------------------------
// K7: edge attention weights (bf16 256B rows; den in qpe row tail).
// ---------------------------------------------------------------------------
__global__ __launch_bounds__(256) void k_edge(const int* __restrict__ ei,
    const ushort* __restrict__ qpe, const ushort* __restrict__ kpe,
    float* __restrict__ A, int E)
{
    int e = blockIdx.x*256 + threadIdx.x;
    if (e >= E) return;
    int s = ei[e], t = ei[E + e];
    const uint4* rq = (const uint4*)(qpe + (size_t)t*128);
    const uint4* rk = (const uint4*)(kpe + (size_t)s*128);
    float num[NH] = {0.f,0.f,0.f,0.f};
    #define ACC2(au,bu,idx0) { \
        float a0=__uint_as_float((au)<<16),        b0=__uint_as_float((bu)<<16); \
        float a1=__uint_as_float((au)&0xffff0000u),b1=__uint_as_float((bu)&0xffff0000u); \
        num[(idx0)/30]     = fmaf(a0,b0,num[(idx0)/30]); \
        num[((idx0)+1)/30] = fmaf(a1,b1,num[((idx0)+1)/30]); }
    #pragma unroll
    for (int j=0;j<15;j++){
        uint4 a = rq[j], b = rk[j];
        ACC2(a.x, b.x, j*8+0)
        ACC2(a.y, b.y, j*8+2)
        ACC2(a.z, b.z, j*8+4)
        ACC2(a.w, b.w, j*8+6)
    }
    #undef ACC2
    float4 dn = *(const float4*)((const float*)qpe + (size_t)t*64 + 60);
    float4 res = make_float4(num[0]/dn.x, num[1]/dn.y, num[2]/dn.z, num[3]/dn.w);
    *(float4*)(A + (size_t)e*4) = res;
}

// ---------------------------------------------------------------------------
extern "C" void kernel_launch(void* const* d_in, const int* in_sizes, int n_in,
                              void* d_out, int out_size, void* d_ws, size_t ws_size,
                              hipStream_t stream)
{
    const float* z    = (const float*)d_in[0];
    const int*   ei   = (const int*)d_in[1];
    const float* gum  = (const float*)d_in[2];
    const float* proj = (const float*)d_in[3];
    const float* Wq   = (const float*)d_in[4];
    const float* bq   = (const float*)d_in[5];
    const float* Wk   = (const float*)d_in[6];
    const float* bk   = (const float*)d_in[7];
    const float* Wv   = (const float*)d_in[8];
    const float* bv   = (const float*)d_in[9];
    const float* Wo   = (const float*)d_in[10];
    const float* Wob  = (const float*)d_in[11];
    int N = in_sizes[0] / NC;
    int E = in_sizes[1] / 2;
    int Npad = (N + 511) & ~511;

    float* ws = (float*)d_ws;
    size_t o = 0;
    #define ALIGN64 o = (o + 63) & ~(size_t)63;
    float* qp       = ws + o; o += (size_t)N*120;
    ALIGN64
    float* vbuf     = ws + o; o += (size_t)N*NHD;
    ALIGN64
    float* dd_k     = ws + o; o += (size_t)NH*N*NM;      // later: egT + kvs_part2
    float* egT      = dd_k;                              // 40*Npad
    float* kvs_part = dd_k + (size_t)40*Npad;            // NSEG*4*20480 fits
    ALIGN64
    float* diag_k   = ws + o; o += (size_t)N*4;
    unsigned* mxk_u = (unsigned*)(ws + o); o += 4;
    ALIGN64
    int nkb = (N+127)/128;
    float* kp_part  = ws + o; o += (size_t)nkb*120;
    float* kp_sum   = ws + o; o += 120;
    ALIGN64
    float* kg_part  = ws + o; o += (size_t)NH*NSEG2*320;
    float* kvs      = ws + o; o += 76800;
    float* kg_sum   = ws + o; o += 1200;
    ALIGN64
    ushort* qpe     = (ushort*)(ws + o); o += (size_t)N*64;
    ALIGN64
    ushort* kpe     = (ushort*)(ws + o); o += (size_t)N*64;
    ALIGN64
    ushort* Wt_h    = (ushort*)(ws + o); o += 48*4*64*8/2;
    ALIGN64
    ushort* Wt_l    = (ushort*)(ws + o); o += 48*4*64*8/2;
    ALIGN64
    float* kpT      = ws + o; o += (size_t)128*Npad;
    ALIGN64
    ushort* WKf_h   = (ushort*)(ws + o); o += 40*4*64*8/2;
    ALIGN64
    ushort* WKf_l   = (ushort*)(ws + o); o += 40*4*64*8/2;
    ALIGN64
    ushort* pf_h    = (ushort*)(ws + o); o += 2048/2;
    ALIGN64
    ushort* pf_l    = (ushort*)(ws + o); o += 2048/2;
    ushort* vT16    = (ushort*)vbuf;                     // dead after k_kvs2

    float* out = (float*)d_out;
    float* A   = out + (size_t)N*ND;

    k_wprep<<<dim3(48), dim3(256), 0, stream>>>(Wq, Wk, Wv, Wt_h, Wt_l);
    k_pprep<<<dim3(1), dim3(256), 0, stream>>>(proj, pf_h, pf_l);
    k_init<<<dim3(1), dim3(64), 0, stream>>>(mxk_u);
    {
        int tail = Npad - N;
        int zwork = 8*Npad + (128+256)*tail;
        k_zfill<<<dim3((zwork+255)/256), dim3(256), 0, stream>>>(kpT, vT16, N, Npad);
    }
    k_qkv<<<dim3((N+15)/16), dim3(256), 0, stream>>>(z, Wt_h, Wt_l, bq, bk, bv,
                                                     pf_h, pf_l,
                                                     qp, qpe, dd_k, diag_k, vT16, N, Npad);
    k_maxred<<<dim3(48,4), dim3(256), 0, stream>>>(dd_k, mxk_u, N);
    k_kp<<<dim3(nkb), dim3(256), 0, stream>>>(dd_k, diag_k, mxk_u, kpe, kpT, kp_part, N, Npad);
    k_kpsred<<<dim3(1), dim3(128), 0, stream>>>(kp_part, kp_sum, nkb);
    k_eg<<<dim3(Npad/64), dim3(256), 0, stream>>>(gum, egT, N, Npad);
    k_kvs2<<<dim3(NSEG, NH), dim3(256), 0, stream>>>(kpT, egT, vT16, kvs_part, Npad);
    k_kgp<<<dim3(NSEG2, NH), dim3(320), 0, stream>>>(kpT, egT, kg_part, Npad);
    k_kvsred2<<<dim3(300), dim3(256), 0, stream>>>(kvs_part, kvs);
    k_kgred2<<<dim3(19), dim3(64), 0, stream>>>(kg_part, kg_sum);
    k_wkprep<<<dim3(40), dim3(256), 0, stream>>>(kvs, Wo, WKf_h, WKf_l);
    k_zo<<<dim3((N+63)/64), dim3(256), 0, stream>>>(qp, WKf_h, WKf_l, kg_sum, kp_sum,
                                                    Wob, qpe, out, N);
    k_edge<<<dim3((E+255)/256), dim3(256), 0, stream>>>(ei, qpe, kpe, A, E);
}